// Round 11
// baseline (490.967 us; speedup 1.0000x reference)
//
#include <hip/hip_runtime.h>
#include <hip/hip_bf16.h>
#include <math.h>

// Problem constants
#define BB 4
#define NN 2048
#define CC 256
#define HH 8
#define DH 32
#define LL 2
#define SS 16
#define KK 33
#define NSAMPLE 32
#define EPSV 1e-5f

typedef _Float16 f16x8 __attribute__((ext_vector_type(8)));
typedef _Float16 f16x4 __attribute__((ext_vector_type(4)));
typedef float f32x4 __attribute__((ext_vector_type(4)));

struct hl16 { _Float16 h, l; };
__device__ __forceinline__ hl16 split2(float v) {
    hl16 r;
    r.h = (_Float16)v;
    r.l = (_Float16)(v - (float)r.h);
    return r;
}

#define INV_MF (1.f / 8192.f)
#define INV_MG (1.f / 2112.f)

// Pre-split weight table offsets (in halves)
#define WT_SLOT 65536
#define FG1H_OFF 1048576
#define FG1L_OFF (FG1H_OFF + 16384)

// ---------------------------------------------------------------------------
// One-time: zero stats regions + split attention weights + fg1 to fp16 hi/lo.
__global__ __launch_bounds__(256) void prep_split_k(
    const float* __restrict__ Wq, const float* __restrict__ Wk,
    const float* __restrict__ Wv, const float* __restrict__ Wo,
    const float* __restrict__ fgw1, _Float16* __restrict__ wt,
    float* __restrict__ stats0) {
    int e = blockIdx.x * 256 + threadIdx.x;
    if (e < 6144) stats0[e] = 0.f;
    if (e < 524288) {
        int slot = e >> 16;  // l*4 + mat
        int l = slot >> 2, mat = slot & 3;
        int r = e & 65535;
        int n = r >> 8, k = r & 255;
        const float* W = mat == 0 ? Wq : mat == 1 ? Wk : mat == 2 ? Wv : Wo;
        hl16 s = split2(W[(size_t)l * 65536 + k * 256 + n]);
        wt[(size_t)(2 * slot) * WT_SLOT + n * 256 + k] = s.h;
        wt[(size_t)(2 * slot + 1) * WT_SLOT + n * 256 + k] = s.l;
    } else if (e < 524288 + 16384) {
        int r = e - 524288;
        hl16 s = split2(fgw1[r]);
        wt[FG1H_OFF + r] = s.h;
        wt[FG1L_OFF + r] = s.l;
    }
}

// ---------------------------------------------------------------------------
__global__ __launch_bounds__(256) void transpose_split_k(const float* __restrict__ in,
                                                         float* __restrict__ out,
                                                         _Float16* __restrict__ oh,
                                                         _Float16* __restrict__ ol) {
    __shared__ float tls[32][33];
    int n0 = blockIdx.x * 32, c0 = blockIdx.y * 32, b = blockIdx.z;
    const float* ip = in + (size_t)b * CC * NN;
    size_t ob = (size_t)b * NN * CC;
    int tx = threadIdx.x, ty = threadIdx.y;
#pragma unroll
    for (int i = 0; i < 4; ++i)
        tls[ty + i * 8][tx] = ip[(size_t)(c0 + ty + i * 8) * NN + n0 + tx];
    __syncthreads();
#pragma unroll
    for (int i = 0; i < 4; ++i) {
        size_t oi = ob + (size_t)(n0 + ty + i * 8) * CC + c0 + tx;
        float v = tls[tx][ty + i * 8];
        out[oi] = v;
        hl16 s = split2(v);
        oh[oi] = s.h;
        ol[oi] = s.l;
    }
}

// ---------------------------------------------------------------------------
// fp32 GEMM with optional fused input-BN+(Leaky)ReLU (staging) and output-stats.
// pst: raw sums of A's channels ([c], [K+c]); ost: raw-sum accumulation for C.
template <bool TRANSB, bool BIAS>
__global__ __launch_bounds__(256) void gemm_k(const float* __restrict__ A,
                                              const float* __restrict__ Bm,
                                              const float* __restrict__ bias,
                                              float* __restrict__ Cm,
                                              int M, int Nc, int K,
                                              const float* __restrict__ pst,
                                              const float* __restrict__ pg,
                                              const float* __restrict__ pb,
                                              float pInvM, float pAlpha,
                                              float* __restrict__ ost) {
    __shared__ float As[16][68];
    __shared__ float Bs[16][68];
    __shared__ float sSc[256], sSh[256];
    int t = threadIdx.x;
    int tx = t & 15, ty = t >> 4;
    int row0 = blockIdx.y * 64, col0 = blockIdx.x * 64;
    if (pst && t < K) {
        float mean = pst[t] * pInvM;
        float var = pst[K + t] * pInvM - mean * mean;
        float wv = rsqrtf(var + EPSV) * pg[t];
        sSc[t] = wv;
        sSh[t] = pb[t] - mean * wv;
    }
    if (pst) __syncthreads();
    float acc[4][4] = {};
    for (int k0 = 0; k0 < K; k0 += 16) {
#pragma unroll
        for (int p = 0; p < 4; ++p) {
            int i = t + 256 * p;
            int m = i >> 4, k = i & 15;
            int gm = row0 + m, gk = k0 + k;
            float av = 0.f;
            if (gm < M && gk < K) {
                av = A[(size_t)gm * K + gk];
                if (pst) {
                    av = fmaf(av, sSc[gk], sSh[gk]);
                    av = av > 0.f ? av : pAlpha * av;
                }
            }
            As[k][m] = av;
        }
#pragma unroll
        for (int p = 0; p < 4; ++p) {
            int i = t + 256 * p;
            if (TRANSB) {
                int k = i & 15, n = i >> 4;
                int gn = col0 + n, gk = k0 + k;
                Bs[k][n] = (gn < Nc && gk < K) ? Bm[(size_t)gn * K + gk] : 0.f;
            } else {
                int n = i & 63, k = i >> 6;
                int gn = col0 + n, gk = k0 + k;
                Bs[k][n] = (gn < Nc && gk < K) ? Bm[(size_t)gk * Nc + gn] : 0.f;
            }
        }
        __syncthreads();
#pragma unroll
        for (int kk = 0; kk < 16; ++kk) {
            float4 a4 = *(const float4*)&As[kk][ty * 4];
            float4 b4 = *(const float4*)&Bs[kk][tx * 4];
            float av[4] = {a4.x, a4.y, a4.z, a4.w};
            float bv[4] = {b4.x, b4.y, b4.z, b4.w};
#pragma unroll
            for (int i = 0; i < 4; ++i)
#pragma unroll
                for (int j = 0; j < 4; ++j) acc[i][j] = fmaf(av[i], bv[j], acc[i][j]);
        }
        __syncthreads();
    }
    float cs[4] = {}, css[4] = {};
#pragma unroll
    for (int i = 0; i < 4; ++i) {
        int r = row0 + ty * 4 + i;
        if (r >= M) continue;
#pragma unroll
        for (int j = 0; j < 4; ++j) {
            int c = col0 + tx * 4 + j;
            if (c >= Nc) continue;
            float v = acc[i][j];
            if (BIAS) v += bias[c];
            Cm[(size_t)r * Nc + c] = v;
            cs[j] += v;
            css[j] += v * v;
        }
    }
    if (ost) {
        float* sc = &As[0][0];  // 128 floats scratch
        if (t < 128) sc[t] = 0.f;
        __syncthreads();
#pragma unroll
        for (int j = 0; j < 4; ++j) {
            atomicAdd(&sc[tx * 4 + j], cs[j]);
            atomicAdd(&sc[64 + tx * 4 + j], css[j]);
        }
        __syncthreads();
        if (t < 64) {
            int c = col0 + t;
            if (c < Nc) {
                atomicAdd(&ost[c], sc[t]);
                atomicAdd(&ost[Nc + c], sc[64 + t]);
            }
        }
    }
}

// ---------------------------------------------------------------------------
// Pre-split fp16 MFMA GEMM. A: Ah/Al [M][K] fp16; B: Bh/Bl [N][K] fp16.
#define EPI_F32 0
#define EPI_QK 1
#define EPI_VT 2

template <int TM>
__device__ __forceinline__ void gemm_h_body(
    const _Float16* __restrict__ Ah, const _Float16* __restrict__ Al,
    const _Float16* __restrict__ Bh, const _Float16* __restrict__ Bl,
    const float* __restrict__ bias, float* __restrict__ Cf,
    _Float16* __restrict__ Ch, _Float16* __restrict__ Cl,
    int Nc, int K, int row0, int col0, int mode, float scl,
    float* __restrict__ ost,
    _Float16* sAh, _Float16* sAl, _Float16* sBh, _Float16* sBl) {
    int t = threadIdx.x, w = t >> 6, lane = t & 63;
    int col = lane & 15, quad = lane >> 4;
    const int m0w = (TM == 128) ? (w & 1) * 64 : 0;
    const int n0w = (TM == 128) ? (w >> 1) * 32 : w * 16;
    constexpr int NT = (TM == 128) ? 2 : 1;
    constexpr int AC = TM / 64;
    f32x4 acc[4][NT];
#pragma unroll
    for (int i = 0; i < 4; ++i)
#pragma unroll
        for (int j = 0; j < NT; ++j) acc[i][j] = (f32x4){0.f, 0.f, 0.f, 0.f};

    for (int k0 = 0; k0 < K; k0 += 32) {
        f16x8 rah[AC], ral[AC], rbh, rbl;
#pragma unroll
        for (int i = 0; i < AC; ++i) {
            int idx = t + 256 * i;
            int r = idx >> 2, off = (idx & 3) * 8;
            rah[i] = *(const f16x8*)(Ah + (size_t)(row0 + r) * K + k0 + off);
            ral[i] = *(const f16x8*)(Al + (size_t)(row0 + r) * K + k0 + off);
        }
        {
            int r = t >> 2, off = (t & 3) * 8;
            rbh = *(const f16x8*)(Bh + (size_t)(col0 + r) * K + k0 + off);
            rbl = *(const f16x8*)(Bl + (size_t)(col0 + r) * K + k0 + off);
        }
        __syncthreads();
#pragma unroll
        for (int i = 0; i < AC; ++i) {
            int idx = t + 256 * i;
            int r = idx >> 2, off = (idx & 3) * 8;
            *(f16x8*)&sAh[r * 40 + off] = rah[i];
            *(f16x8*)&sAl[r * 40 + off] = ral[i];
        }
        {
            int r = t >> 2, off = (t & 3) * 8;
            *(f16x8*)&sBh[r * 40 + off] = rbh;
            *(f16x8*)&sBl[r * 40 + off] = rbl;
        }
        __syncthreads();
        f16x8 fah[4], fal[4], fbh[NT], fbl[NT];
#pragma unroll
        for (int i = 0; i < 4; ++i) {
            fah[i] = *(const f16x8*)&sAh[(m0w + i * 16 + col) * 40 + quad * 8];
            fal[i] = *(const f16x8*)&sAl[(m0w + i * 16 + col) * 40 + quad * 8];
        }
#pragma unroll
        for (int j = 0; j < NT; ++j) {
            fbh[j] = *(const f16x8*)&sBh[(n0w + j * 16 + col) * 40 + quad * 8];
            fbl[j] = *(const f16x8*)&sBl[(n0w + j * 16 + col) * 40 + quad * 8];
        }
#pragma unroll
        for (int i = 0; i < 4; ++i)
#pragma unroll
            for (int j = 0; j < NT; ++j) {
                acc[i][j] = __builtin_amdgcn_mfma_f32_16x16x32_f16(fah[i], fbh[j], acc[i][j], 0, 0, 0);
                acc[i][j] = __builtin_amdgcn_mfma_f32_16x16x32_f16(fah[i], fbl[j], acc[i][j], 0, 0, 0);
                acc[i][j] = __builtin_amdgcn_mfma_f32_16x16x32_f16(fal[i], fbh[j], acc[i][j], 0, 0, 0);
            }
    }
    float s = 0.f, ss = 0.f;
#pragma unroll
    for (int i = 0; i < 4; ++i)
#pragma unroll
        for (int j = 0; j < NT; ++j) {
            int n = col0 + n0w + j * 16 + col;
            int mb = row0 + m0w + i * 16 + quad * 4;
            if (mode == EPI_F32) {
                float bv = bias ? bias[n] : 0.f;
#pragma unroll
                for (int r = 0; r < 4; ++r) {
                    float v = acc[i][j][r] + bv;
                    Cf[(size_t)(mb + r) * Nc + n] = v;
                    s += v;
                    ss += v * v;
                }
            } else if (mode == EPI_QK) {
#pragma unroll
                for (int r = 0; r < 4; ++r) {
                    hl16 sp = split2(acc[i][j][r] * scl);
                    Ch[(size_t)(mb + r) * Nc + n] = sp.h;
                    Cl[(size_t)(mb + r) * Nc + n] = sp.l;
                }
            } else {  // EPI_VT: [b][h][d][token]
                int b = mb >> 11, token = mb & 2047;
                int h = n >> 5, d = n & 31;
                f16x4 h4, l4;
#pragma unroll
                for (int r = 0; r < 4; ++r) {
                    hl16 sp = split2(acc[i][j][r]);
                    h4[r] = sp.h;
                    l4[r] = sp.l;
                }
                size_t dst = ((size_t)(b * HH + h) * DH + d) * NN + token;
                *(f16x4*)&Ch[dst] = h4;
                *(f16x4*)&Cl[dst] = l4;
            }
        }
    if (ost && mode == EPI_F32 && TM == 64) {
        s += __shfl_xor(s, 16);
        s += __shfl_xor(s, 32);
        ss += __shfl_xor(ss, 16);
        ss += __shfl_xor(ss, 32);
        if (quad == 0) {
            int n = col0 + n0w + col;
            atomicAdd(&ost[n], s);
            atomicAdd(&ost[Nc + n], ss);
        }
    }
}

template <int TM>
__global__ __launch_bounds__(256) void gemm_h_k(const _Float16* __restrict__ Ah,
                                                const _Float16* __restrict__ Al,
                                                const _Float16* __restrict__ Bh,
                                                const _Float16* __restrict__ Bl,
                                                const float* __restrict__ bias,
                                                float* __restrict__ Cf, int Nc, int K,
                                                float* __restrict__ ost) {
    __shared__ _Float16 sAh[TM * 40], sAl[TM * 40], sBh[64 * 40], sBl[64 * 40];
    gemm_h_body<TM>(Ah, Al, Bh, Bl, bias, Cf, nullptr, nullptr, Nc, K,
                    blockIdx.y * TM, blockIdx.x * 64, EPI_F32, 1.f, ost,
                    sAh, sAl, sBh, sBl);
}

// Fused QKV: blockIdx.x in [0,12): mat = x>>2, col block = x&3.
// Q scale folds 1/sqrt(dh) AND log2(e) (softmax uses exp2).
__global__ __launch_bounds__(256) void qkv_h_k(const _Float16* __restrict__ Xh,
                                               const _Float16* __restrict__ Xl,
                                               const _Float16* __restrict__ wt, int layer,
                                               _Float16* Qh, _Float16* Ql,
                                               _Float16* Kh, _Float16* Kl,
                                               _Float16* Vh, _Float16* Vl) {
    __shared__ _Float16 sAh[128 * 40], sAl[128 * 40], sBh[64 * 40], sBl[64 * 40];
    int mat = blockIdx.x >> 2;
    int slot = (layer * 4 + mat) * 2;
    const _Float16* Bh = wt + (size_t)slot * WT_SLOT;
    const _Float16* Bl = wt + (size_t)(slot + 1) * WT_SLOT;
    _Float16* Ch = mat == 0 ? Qh : mat == 1 ? Kh : Vh;
    _Float16* Cl = mat == 0 ? Ql : mat == 1 ? Kl : Vl;
    int mode = (mat == 2) ? EPI_VT : EPI_QK;
    float scl = (mat == 0) ? 0.25501654859214384f : 1.f;  // 1/sqrt(32)*log2(e)
    gemm_h_body<128>(Xh, Xl, Bh, Bl, nullptr, nullptr, Ch, Cl, CC, CC,
                     blockIdx.y * 128, (blockIdx.x & 3) * 64, mode, scl, nullptr,
                     sAh, sAl, sBh, sBl);
}

// ---------------------------------------------------------------------------
// Wo GEMM with fused attention-partial combine: A rows assembled on the fly
// from O0/O1 (unnormalized partials) + (m,l) via exact online-softmax merge.
__global__ __launch_bounds__(256) void gemm_wo_k(const float* __restrict__ O0,
                                                 const float* __restrict__ O1,
                                                 const float* __restrict__ ML,
                                                 const _Float16* __restrict__ Bh,
                                                 const _Float16* __restrict__ Bl,
                                                 float* __restrict__ Cf) {
    __shared__ _Float16 sAh[128 * 40], sAl[128 * 40], sBh[64 * 40], sBl[64 * 40];
    int t = threadIdx.x, w = t >> 6, lane = t & 63;
    int col = lane & 15, quad = lane >> 4;
    int m0w = (w & 1) * 64, n0w = (w >> 1) * 32;
    int row0 = blockIdx.y * 128, col0 = blockIdx.x * 64;
    const float2* mlp = (const float2*)ML;
    f32x4 acc[4][2];
#pragma unroll
    for (int i = 0; i < 4; ++i)
#pragma unroll
        for (int j = 0; j < 2; ++j) acc[i][j] = (f32x4){0.f, 0.f, 0.f, 0.f};

    for (int k0 = 0; k0 < CC; k0 += 32) {
        int h = k0 >> 5;
        float av[2][8];
#pragma unroll
        for (int i = 0; i < 2; ++i) {
            int idx = t + 256 * i;
            int r = idx >> 2, off = (idx & 3) * 8;
            int m = row0 + r;
            int b = m >> 11, token = m & 2047;
            int qi = ((b * HH + h) << 11) | token;
            float2 ml0 = mlp[qi];
            float2 ml1 = mlp[BB * HH * NN + qi];
            float mm = fmaxf(ml0.x, ml1.x);
            float a0 = __builtin_amdgcn_exp2f(ml0.x - mm);
            float a1 = __builtin_amdgcn_exp2f(ml1.x - mm);
            float inv = 1.f / (ml0.y * a0 + ml1.y * a1);
            a0 *= inv;
            a1 *= inv;
            size_t so = (size_t)qi * 32 + off;
            float4 p0 = *(const float4*)&O0[so];
            float4 p0b = *(const float4*)&O0[so + 4];
            float4 p1 = *(const float4*)&O1[so];
            float4 p1b = *(const float4*)&O1[so + 4];
            av[i][0] = p0.x * a0 + p1.x * a1;
            av[i][1] = p0.y * a0 + p1.y * a1;
            av[i][2] = p0.z * a0 + p1.z * a1;
            av[i][3] = p0.w * a0 + p1.w * a1;
            av[i][4] = p0b.x * a0 + p1b.x * a1;
            av[i][5] = p0b.y * a0 + p1b.y * a1;
            av[i][6] = p0b.z * a0 + p1b.z * a1;
            av[i][7] = p0b.w * a0 + p1b.w * a1;
        }
        f16x8 rbh, rbl;
        {
            int r = t >> 2, off = (t & 3) * 8;
            rbh = *(const f16x8*)(Bh + (size_t)(col0 + r) * CC + k0 + off);
            rbl = *(const f16x8*)(Bl + (size_t)(col0 + r) * CC + k0 + off);
        }
        __syncthreads();
#pragma unroll
        for (int i = 0; i < 2; ++i) {
            int idx = t + 256 * i;
            int r = idx >> 2, off = (idx & 3) * 8;
            f16x8 h8, l8;
#pragma unroll
            for (int j = 0; j < 8; ++j) {
                hl16 s = split2(av[i][j]);
                h8[j] = s.h;
                l8[j] = s.l;
            }
            *(f16x8*)&sAh[r * 40 + off] = h8;
            *(f16x8*)&sAl[r * 40 + off] = l8;
        }
        {
            int r = t >> 2, off = (t & 3) * 8;
            *(f16x8*)&sBh[r * 40 + off] = rbh;
            *(f16x8*)&sBl[r * 40 + off] = rbl;
        }
        __syncthreads();
        f16x8 fah[4], fal[4], fbh[2], fbl[2];
#pragma unroll
        for (int i = 0; i < 4; ++i) {
            fah[i] = *(const f16x8*)&sAh[(m0w + i * 16 + col) * 40 + quad * 8];
            fal[i] = *(const f16x8*)&sAl[(m0w + i * 16 + col) * 40 + quad * 8];
        }
#pragma unroll
        for (int j = 0; j < 2; ++j) {
            fbh[j] = *(const f16x8*)&sBh[(n0w + j * 16 + col) * 40 + quad * 8];
            fbl[j] = *(const f16x8*)&sBl[(n0w + j * 16 + col) * 40 + quad * 8];
        }
#pragma unroll
        for (int i = 0; i < 4; ++i)
#pragma unroll
            for (int j = 0; j < 2; ++j) {
                acc[i][j] = __builtin_amdgcn_mfma_f32_16x16x32_f16(fah[i], fbh[j], acc[i][j], 0, 0, 0);
                acc[i][j] = __builtin_amdgcn_mfma_f32_16x16x32_f16(fah[i], fbl[j], acc[i][j], 0, 0, 0);
                acc[i][j] = __builtin_amdgcn_mfma_f32_16x16x32_f16(fal[i], fbh[j], acc[i][j], 0, 0, 0);
            }
    }
#pragma unroll
    for (int i = 0; i < 4; ++i)
#pragma unroll
        for (int j = 0; j < 2; ++j) {
            int n = col0 + n0w + j * 16 + col;
            int mb = row0 + m0w + i * 16 + quad * 4;
#pragma unroll
            for (int r = 0; r < 4; ++r)
                Cf[(size_t)(mb + r) * CC + n] = acc[i][j][r];
        }
}

// ---------------------------------------------------------------------------
// Attention v6: flash-decode key split. Grid (NN/64 qblk, 2 key-halves, B*H).
__global__ __launch_bounds__(256) void attn6_k(const _Float16* __restrict__ Qhp,
                                               const _Float16* __restrict__ Qlp,
                                               const _Float16* __restrict__ Kh,
                                               const _Float16* __restrict__ Kl,
                                               const _Float16* __restrict__ Vh,
                                               const _Float16* __restrict__ Vl,
                                               float* __restrict__ O0,
                                               float* __restrict__ O1,
                                               float* __restrict__ ML) {
    __shared__ _Float16 sKh[64 * 40], sKl[64 * 40];   // [key][d]
    __shared__ _Float16 sVh[32 * 72], sVl[32 * 72];   // [d][key]
    __shared__ _Float16 sPh[4][16 * 40], sPl[4][16 * 40];  // per-wave, 32-key chunk
    int t = threadIdx.x, w = t >> 6, lane = t & 63;
    int col = lane & 15, quad = lane >> 4;
    int bh = blockIdx.z, b = bh >> 3, h = bh & 7;
    int kh = blockIdx.y;
    int qbase = blockIdx.x * 64 + w * 16;

    size_t qoff = ((size_t)(b * NN + qbase + col)) * CC + h * DH + quad * 8;
    f16x8 qh = *(const f16x8*)(Qhp + qoff);
    f16x8 ql = *(const f16x8*)(Qlp + qoff);

    f32x4 o0 = {0.f, 0.f, 0.f, 0.f}, o1 = {0.f, 0.f, 0.f, 0.f};
    float mrun = -1e30f, lsum = 0.f;

    const _Float16* fKh = &sKh[col * 40 + quad * 8];
    const _Float16* fKl = &sKl[col * 40 + quad * 8];
    const _Float16* fVh0 = &sVh[col * 72 + quad * 8];
    const _Float16* fVl0 = &sVl[col * 72 + quad * 8];
    const _Float16* fVh1 = &sVh[(16 + col) * 72 + quad * 8];
    const _Float16* fVl1 = &sVl[(16 + col) * 72 + quad * 8];
    _Float16* wPh = &sPh[w][col * 40 + quad * 4];
    _Float16* wPl = &sPl[w][col * 40 + quad * 4];
    const _Float16* rPh = &sPh[w][col * 40 + quad * 8];
    const _Float16* rPl = &sPl[w][col * 40 + quad * 8];

    int pidx = t & 127;
    int krow = pidx >> 1, koff = (pidx & 1) * 16;   // K: [key][d], 64x32 halves
    int vrow = pidx >> 2, voff = (pidx & 3) * 16;   // V: [d][key], 32x64 halves
    const _Float16* kg = (t < 128 ? Kh : Kl) + (size_t)b * NN * CC + h * DH;
    const _Float16* vg = (t < 128 ? Vh : Vl) + ((size_t)(b * HH + h) * DH + vrow) * NN;
    _Float16* dK = (t < 128 ? sKh : sKl) + krow * 40 + koff;
    _Float16* dV = (t < 128 ? sVh : sVl) + vrow * 72 + voff;

    int kbase = kh * (NN / 2);
    for (int k0 = kbase; k0 < kbase + NN / 2; k0 += 64) {
        const _Float16* kp = kg + (size_t)(k0 + krow) * CC + koff;
        f16x8 rk0 = *(const f16x8*)kp;
        f16x8 rk1 = *(const f16x8*)(kp + 8);
        const _Float16* vp = vg + k0 + voff;
        f16x8 rv0 = *(const f16x8*)vp;
        f16x8 rv1 = *(const f16x8*)(vp + 8);
        __syncthreads();
        *(f16x8*)dK = rk0;
        *(f16x8*)(dK + 8) = rk1;
        *(f16x8*)dV = rv0;
        *(f16x8*)(dV + 8) = rv1;
        __syncthreads();

        f32x4 s[4];
#pragma unroll
        for (int kt = 0; kt < 4; ++kt) {
            f16x8 ka = *(const f16x8*)(fKh + kt * 16 * 40);
            f16x8 kb = *(const f16x8*)(fKl + kt * 16 * 40);
            f32x4 z = {0.f, 0.f, 0.f, 0.f};
            z = __builtin_amdgcn_mfma_f32_16x16x32_f16(ka, qh, z, 0, 0, 0);
            z = __builtin_amdgcn_mfma_f32_16x16x32_f16(ka, ql, z, 0, 0, 0);
            z = __builtin_amdgcn_mfma_f32_16x16x32_f16(kb, qh, z, 0, 0, 0);
            s[kt] = z;
        }

        float tm = -1e30f;
#pragma unroll
        for (int kt = 0; kt < 4; ++kt)
#pragma unroll
            for (int r = 0; r < 4; ++r) tm = fmaxf(tm, s[kt][r]);
        tm = fmaxf(tm, __shfl_xor(tm, 16));
        tm = fmaxf(tm, __shfl_xor(tm, 32));
        float nm = fmaxf(mrun, tm);
        float alpha = __builtin_amdgcn_exp2f(mrun - nm);
        float p[16], rs = 0.f;
#pragma unroll
        for (int kt = 0; kt < 4; ++kt)
#pragma unroll
            for (int r = 0; r < 4; ++r) {
                float pv = __builtin_amdgcn_exp2f(s[kt][r] - nm);
                p[kt * 4 + r] = pv;
                rs += pv;
            }
        rs += __shfl_xor(rs, 16);
        rs += __shfl_xor(rs, 32);
        lsum = lsum * alpha + rs;
        mrun = nm;
        o0.x *= alpha; o0.y *= alpha; o0.z *= alpha; o0.w *= alpha;
        o1.x *= alpha; o1.y *= alpha; o1.z *= alpha; o1.w *= alpha;

#pragma unroll
        for (int c = 0; c < 2; ++c) {
#pragma unroll
            for (int k2 = 0; k2 < 2; ++k2) {
                int kt = c * 2 + k2;
                f16x4 h4, l4;
#pragma unroll
                for (int r = 0; r < 4; ++r) {
                    hl16 sp = split2(p[kt * 4 + r]);
                    h4[r] = sp.h;
                    l4[r] = sp.l;
                }
                *(f16x4*)(wPh + k2 * 16) = h4;
                *(f16x4*)(wPl + k2 * 16) = l4;
            }
            __asm__ volatile("s_waitcnt lgkmcnt(0)" ::: "memory");
            f16x8 pH = *(const f16x8*)rPh;
            f16x8 pL = *(const f16x8*)rPl;

            f16x8 va = *(const f16x8*)(fVh0 + c * 32);
            f16x8 vb = *(const f16x8*)(fVl0 + c * 32);
            o0 = __builtin_amdgcn_mfma_f32_16x16x32_f16(va, pH, o0, 0, 0, 0);
            o0 = __builtin_amdgcn_mfma_f32_16x16x32_f16(va, pL, o0, 0, 0, 0);
            o0 = __builtin_amdgcn_mfma_f32_16x16x32_f16(vb, pH, o0, 0, 0, 0);
            f16x8 vc = *(const f16x8*)(fVh1 + c * 32);
            f16x8 vd = *(const f16x8*)(fVl1 + c * 32);
            o1 = __builtin_amdgcn_mfma_f32_16x16x32_f16(vc, pH, o1, 0, 0, 0);
            o1 = __builtin_amdgcn_mfma_f32_16x16x32_f16(vc, pL, o1, 0, 0, 0);
            o1 = __builtin_amdgcn_mfma_f32_16x16x32_f16(vd, pH, o1, 0, 0, 0);
        }
    }

    float* OP = (kh == 0) ? O0 : O1;
    int q = qbase + col;
    size_t oi = ((size_t)bh * NN + q) * 32;
    *(f32x4*)&OP[oi + quad * 4] = o0;
    *(f32x4*)&OP[oi + 16 + quad * 4] = o1;
    if (quad == 0) {
        float2* mlp = (float2*)ML;
        mlp[(size_t)kh * (BB * HH * NN) + (size_t)bh * NN + q] = make_float2(mrun, lsum);
    }
}

// ---------------------------------------------------------------------------
__global__ __launch_bounds__(256) void add_ln_k(float* __restrict__ X,
                                                const float* __restrict__ P,
                                                const float* __restrict__ g,
                                                const float* __restrict__ bta,
                                                _Float16* __restrict__ Xh,
                                                _Float16* __restrict__ Xl) {
    int wave = threadIdx.x >> 6, lane = threadIdx.x & 63;
    size_t row = (size_t)blockIdx.x * 4 + wave;
    size_t base = row * CC + lane * 4;
    float4 x = *(float4*)(X + base);
    float4 p = *(const float4*)(P + base);
    x.x += p.x; x.y += p.y; x.z += p.z; x.w += p.w;
    float sum = x.x + x.y + x.z + x.w;
    float ss = x.x * x.x + x.y * x.y + x.z * x.z + x.w * x.w;
#pragma unroll
    for (int off = 32; off; off >>= 1) {
        sum += __shfl_down(sum, off);
        ss += __shfl_down(ss, off);
    }
    sum = __shfl(sum, 0);
    ss = __shfl(ss, 0);
    float mean = sum * (1.f / 256.f);
    float var = ss * (1.f / 256.f) - mean * mean;
    float wn = rsqrtf(var + EPSV);
    float4 gg = *(const float4*)(g + lane * 4);
    float4 bb = *(const float4*)(bta + lane * 4);
    x.x = (x.x - mean) * wn * gg.x + bb.x;
    x.y = (x.y - mean) * wn * gg.y + bb.y;
    x.z = (x.z - mean) * wn * gg.z + bb.z;
    x.w = (x.w - mean) * wn * gg.w + bb.w;
    *(float4*)(X + base) = x;
    f16x4 h4, l4;
    float xv[4] = {x.x, x.y, x.z, x.w};
#pragma unroll
    for (int j = 0; j < 4; ++j) {
        hl16 s = split2(xv[j]);
        h4[j] = s.h;
        l4[j] = s.l;
    }
    *(f16x4*)&Xh[base] = h4;
    *(f16x4*)&Xl[base] = l4;
}

// ---------------------------------------------------------------------------
// Fused: BN3(raw sums)+ReLU -> argmax -> ball query -> gather grouped coords.
__global__ __launch_bounds__(64) void select_k(const float* __restrict__ H3,
                                               const float* __restrict__ pts,
                                               const float* __restrict__ st,
                                               const float* __restrict__ gam,
                                               const float* __restrict__ bet,
                                               float* __restrict__ G0) {
    int bs = blockIdx.x;
    int b = bs >> 4, ch = bs & 15;
    int lane = threadIdx.x;
    float mean = st[ch] * INV_MF;
    float var = st[16 + ch] * INV_MF - mean * mean;
    float sc = rsqrtf(var + EPSV) * gam[ch];
    float sh = bet[ch] - mean * sc;
    float best = -1e30f;
    int bn = 0;
    for (int n = lane; n < NN; n += 64) {
        float v = fmaf(H3[((size_t)(b * NN + n)) * 16 + ch], sc, sh);
        v = fmaxf(v, 0.f);
        if (v > best) { best = v; bn = n; }
    }
#pragma unroll
    for (int off = 32; off; off >>= 1) {
        float ov = __shfl_xor(best, off);
        int on = __shfl_xor(bn, off);
        if (ov > best || (ov == best && on < bn)) { best = ov; bn = on; }
    }
    const float* px = pts + (size_t)b * 3 * NN;
    float qx = px[bn], qy = px[NN + bn], qz = px[2 * NN + bn];
    float qq = (qx * qx + qy * qy) + qz * qz;
    __shared__ int sgi[NSAMPLE];
    const float R2 = 0.09f;
    int cnt = 0;
    for (int base = 0; base < NN && cnt < NSAMPLE; base += 64) {
        int n = base + lane;
        float x = px[n], y = px[NN + n], z = px[2 * NN + n];
        float pp = (x * x + y * y) + z * z;
        float dot = (qx * x + qy * y) + qz * z;
        float sqd = (qq + pp) - 2.f * dot;
        bool ok = !(sqd > R2);
        unsigned long long mk = __ballot(ok);
        int pos = cnt + (int)__popcll(mk & ((1ull << lane) - 1ull));
        if (ok && pos < NSAMPLE) sgi[pos] = n;
        cnt += (int)__popcll(mk);
    }
    __syncthreads();
    int g0 = sgi[0];
    if (lane >= cnt && lane < NSAMPLE) sgi[lane] = g0;
    __syncthreads();
    for (int e = lane; e < KK * 3; e += 64) {
        int k = e / 3, d = e % 3;
        int src = (k == 0) ? bn : sgi[k - 1];
        G0[((size_t)bs * KK + k) * 3 + d] = px[d * NN + src];
    }
}

// ---------------------------------------------------------------------------
// Fused BN(C3, raw sums)+LeakyReLU+max over k.
__global__ __launch_bounds__(256) void maxpool_k(const float* __restrict__ G3,
                                                 const float* __restrict__ st,
                                                 const float* __restrict__ gam,
                                                 const float* __restrict__ bet,
                                                 float* __restrict__ out) {
    int i = blockIdx.x * 256 + threadIdx.x;
    if (i >= BB * 512 * SS) return;
    int o = i & 511;
    int s = (i >> 9) & 15;
    int b = i >> 13;
    float mean = st[o] * INV_MG;
    float var = st[512 + o] * INV_MG - mean * mean;
    float sc = rsqrtf(var + EPSV) * gam[o];
    float sh = bet[o] - mean * sc;
    const float* p = G3 + ((size_t)(b * SS + s) * KK) * 512 + o;
    float mx = -1e30f;
#pragma unroll
    for (int k = 0; k < KK; ++k) {
        float v = fmaf(p[(size_t)k * 512], sc, sh);
        v = v > 0.f ? v : 0.2f * v;
        mx = fmaxf(mx, v);
    }
    out[((size_t)(b * 512 + o)) * SS + s] = mx;
}

// ---------------------------------------------------------------------------
extern "C" void kernel_launch(void* const* d_in, const int* in_sizes, int n_in,
                              void* d_out, int out_size, void* d_ws, size_t ws_size,
                              hipStream_t stream) {
    const float* hoch = (const float*)d_in[0];
    const float* pts = (const float*)d_in[1];
    const float* Wq = (const float*)d_in[2];
    const float* Wk = (const float*)d_in[3];
    const float* Wv = (const float*)d_in[4];
    const float* Wo = (const float*)d_in[5];
    const float* ln_g = (const float*)d_in[6];
    const float* ln_b = (const float*)d_in[7];
    const float* fg_w1 = (const float*)d_in[8];
    const float* fg_b1 = (const float*)d_in[9];
    const float* fg_w2 = (const float*)d_in[10];
    const float* fg_b2 = (const float*)d_in[11];
    const float* fg_w3 = (const float*)d_in[12];
    const float* fg_b3 = (const float*)d_in[13];
    const float* fg_g1 = (const float*)d_in[14];
    const float* fg_be1 = (const float*)d_in[15];
    const float* fg_g2 = (const float*)d_in[16];
    const float* fg_be2 = (const float*)d_in[17];
    const float* fg_g3 = (const float*)d_in[18];
    const float* fg_be3 = (const float*)d_in[19];
    const float* cw1 = (const float*)d_in[20];
    const float* cw2 = (const float*)d_in[21];
    const float* cw3 = (const float*)d_in[22];
    const float* cg1 = (const float*)d_in[23];
    const float* cb1 = (const float*)d_in[24];
    const float* cg2 = (const float*)d_in[25];
    const float* cb2 = (const float*)d_in[26];
    const float* cg3 = (const float*)d_in[27];
    const float* cb3 = (const float*)d_in[28];
    float* out = (float*)d_out;

    float* ws = (float*)d_ws;
    const size_t M1 = (size_t)BB * NN * CC;  // 2,097,152
    float* X = ws;
    float* bA = ws + M1;       // attention (m,l) partials / fg+conv scratch
    float* bB = ws + 2 * M1;   // attention O partial (key-half 0) / scratch
    float* bC = ws + 3 * M1;   // attention O partial (key-half 1) / scratch
    _Float16* hb = (_Float16*)(ws + 4 * M1);
    _Float16* Xh = hb;
    _Float16* Xl = hb + M1;
    _Float16* Qh = hb + 2 * M1;  // Q; dead after attn6 -> reused as Wo fp32 out
    _Float16* Ql = hb + 3 * M1;
    _Float16* Kh = hb + 4 * M1;
    _Float16* Kl = hb + 5 * M1;
    _Float16* Vh = hb + 6 * M1;
    _Float16* Vl = hb + 7 * M1;
    _Float16* wt = hb + 8 * M1;  // 1,081,344 halves
    float* sm = ws + 4 * M1 + (9 * M1) / 2;
    float* st1 = sm;
    float* st2 = sm + 1024;
    float* st3 = sm + 2048;
    float* st4 = sm + 3072;
    float* st5 = sm + 4096;
    float* st6 = sm + 5120;
    float* G0 = sm + 8192;  // 6336

    prep_split_k<<<2112, 256, 0, stream>>>(Wq, Wk, Wv, Wo, fg_w1, wt, sm);
    transpose_split_k<<<dim3(NN / 32, CC / 32, BB), dim3(32, 8), 0, stream>>>(hoch, X, Xh, Xl);

    const int Mrows = BB * NN;  // 8192
    float* woOut = (float*)Qh;  // Qh+Ql region = M1 floats, dead after attn6
    for (int l = 0; l < LL; ++l) {
        qkv_h_k<<<dim3(12, Mrows / 128), 256, 0, stream>>>(Xh, Xl, wt, l, Qh, Ql, Kh, Kl, Vh, Vl);
        attn6_k<<<dim3(NN / 64, 2, BB * HH), 256, 0, stream>>>(Qh, Ql, Kh, Kl, Vh, Vl, bB, bC, bA);
        int slot = (l * 4 + 3) * 2;
        gemm_wo_k<<<dim3(CC / 64, Mrows / 128), 256, 0, stream>>>(
            bB, bC, bA, wt + (size_t)slot * WT_SLOT, wt + (size_t)(slot + 1) * WT_SLOT, woOut);
        add_ln_k<<<Mrows / 4, 256, 0, stream>>>(X, woOut, ln_g + l * CC, ln_b + l * CC, Xh, Xl);
    }

    // fg head: 256 -> 64 -> 32 -> 16; stats fused in epilogues, BN fused forward
    gemm_h_k<64><<<dim3(1, Mrows / 64), 256, 0, stream>>>(Xh, Xl, wt + FG1H_OFF, wt + FG1L_OFF, fg_b1, bA, 64, 256, st1);
    gemm_k<true, true><<<dim3(1, Mrows / 64), 256, 0, stream>>>(bA, fg_w2, fg_b2, bB, Mrows, 32, 64,
                                                                st1, fg_g1, fg_be1, INV_MF, 0.f, st2);
    gemm_k<true, true><<<dim3(1, Mrows / 64), 256, 0, stream>>>(bB, fg_w3, fg_b3, bC, Mrows, 16, 32,
                                                                st2, fg_g2, fg_be2, INV_MF, 0.f, st3);

    // selection + grouping (applies BN3+ReLU internally)
    select_k<<<BB * SS, 64, 0, stream>>>(bC, pts, st3, fg_g3, fg_be3, G0);

    // conv stack (fp32, input-BN+LeakyReLU fused into staging): 3 -> 64 -> 256 -> 512
    const int Mg = BB * SS * KK;  // 2112 = 33*64
    gemm_k<true, false><<<dim3(1, Mg / 64), 256, 0, stream>>>(G0, cw1, nullptr, bA, Mg, 64, 3,
                                                              nullptr, nullptr, nullptr, 0.f, 0.f, st4);
    gemm_k<true, false><<<dim3(4, Mg / 64), 256, 0, stream>>>(bA, cw2, nullptr, bB, Mg, 256, 64,
                                                              st4, cg1, cb1, INV_MG, 0.2f, st5);
    gemm_k<true, false><<<dim3(8, Mg / 64), 256, 0, stream>>>(bB, cw3, nullptr, bC, Mg, 512, 256,
                                                              st5, cg2, cb2, INV_MG, 0.2f, st6);

    // fused BN(C3)+LeakyReLU+maxpool
    maxpool_k<<<(BB * 512 * SS + 255) / 256, 256, 0, stream>>>(bC, st6, cg3, cb3, out);

    (void)in_sizes; (void)n_in; (void)out_size; (void)ws_size;
}

// Round 12
// 470.906 us; speedup vs baseline: 1.0426x; 1.0426x over previous
//
#include <hip/hip_runtime.h>
#include <hip/hip_bf16.h>
#include <math.h>

// Problem constants
#define BB 4
#define NN 2048
#define CC 256
#define HH 8
#define DH 32
#define LL 2
#define SS 16
#define KK 33
#define NSAMPLE 32
#define EPSV 1e-5f

typedef _Float16 f16x8 __attribute__((ext_vector_type(8)));
typedef _Float16 f16x4 __attribute__((ext_vector_type(4)));
typedef float f32x4 __attribute__((ext_vector_type(4)));

struct hl16 { _Float16 h, l; };
__device__ __forceinline__ hl16 split2(float v) {
    hl16 r;
    r.h = (_Float16)v;
    r.l = (_Float16)(v - (float)r.h);
    return r;
}

#define INV_MF (1.f / 8192.f)
#define INV_MG (1.f / 2112.f)

// Pre-split weight table offsets (in halves)
#define WT_SLOT 65536
#define FG1H_OFF 1048576
#define FG1L_OFF (FG1H_OFF + 16384)
#define CW2H_OFF (FG1H_OFF + 32768)
#define CW2L_OFF (FG1H_OFF + 49152)
#define CW3H_OFF (FG1H_OFF + 65536)
#define CW3L_OFF (CW3H_OFF + 131072)

// ---------------------------------------------------------------------------
// One-time: zero stats regions + split all MFMA-path weights to fp16 hi/lo.
__global__ __launch_bounds__(256) void prep_split_k(
    const float* __restrict__ Wq, const float* __restrict__ Wk,
    const float* __restrict__ Wv, const float* __restrict__ Wo,
    const float* __restrict__ fgw1, const float* __restrict__ cw2,
    const float* __restrict__ cw3, _Float16* __restrict__ wt,
    float* __restrict__ stats0) {
    int e = blockIdx.x * 256 + threadIdx.x;
    if (e < 6144) stats0[e] = 0.f;
    if (e < 524288) {
        int slot = e >> 16;  // l*4 + mat
        int l = slot >> 2, mat = slot & 3;
        int r = e & 65535;
        int n = r >> 8, k = r & 255;
        const float* W = mat == 0 ? Wq : mat == 1 ? Wk : mat == 2 ? Wv : Wo;
        hl16 s = split2(W[(size_t)l * 65536 + k * 256 + n]);
        wt[(size_t)(2 * slot) * WT_SLOT + n * 256 + k] = s.h;
        wt[(size_t)(2 * slot + 1) * WT_SLOT + n * 256 + k] = s.l;
    } else if (e < 524288 + 16384) {
        int r = e - 524288;
        hl16 s = split2(fgw1[r]);
        wt[FG1H_OFF + r] = s.h;
        wt[FG1L_OFF + r] = s.l;
    } else if (e < 524288 + 32768) {
        int r = e - (524288 + 16384);
        hl16 s = split2(cw2[r]);
        wt[CW2H_OFF + r] = s.h;
        wt[CW2L_OFF + r] = s.l;
    } else if (e < 524288 + 32768 + 131072) {
        int r = e - (524288 + 32768);
        hl16 s = split2(cw3[r]);
        wt[CW3H_OFF + r] = s.h;
        wt[CW3L_OFF + r] = s.l;
    }
}

// ---------------------------------------------------------------------------
__global__ __launch_bounds__(256) void transpose_split_k(const float* __restrict__ in,
                                                         float* __restrict__ out,
                                                         _Float16* __restrict__ oh,
                                                         _Float16* __restrict__ ol) {
    __shared__ float tls[32][33];
    int n0 = blockIdx.x * 32, c0 = blockIdx.y * 32, b = blockIdx.z;
    const float* ip = in + (size_t)b * CC * NN;
    size_t ob = (size_t)b * NN * CC;
    int tx = threadIdx.x, ty = threadIdx.y;
#pragma unroll
    for (int i = 0; i < 4; ++i)
        tls[ty + i * 8][tx] = ip[(size_t)(c0 + ty + i * 8) * NN + n0 + tx];
    __syncthreads();
#pragma unroll
    for (int i = 0; i < 4; ++i) {
        size_t oi = ob + (size_t)(n0 + ty + i * 8) * CC + c0 + tx;
        float v = tls[tx][ty + i * 8];
        out[oi] = v;
        hl16 s = split2(v);
        oh[oi] = s.h;
        ol[oi] = s.l;
    }
}

// ---------------------------------------------------------------------------
// fp32 GEMM with optional fused input-BN+ReLU (staging) and output-stats.
template <bool TRANSB, bool BIAS>
__global__ __launch_bounds__(256) void gemm_k(const float* __restrict__ A,
                                              const float* __restrict__ Bm,
                                              const float* __restrict__ bias,
                                              float* __restrict__ Cm,
                                              int M, int Nc, int K,
                                              const float* __restrict__ pst,
                                              const float* __restrict__ pg,
                                              const float* __restrict__ pb,
                                              float pInvM,
                                              float* __restrict__ ost) {
    __shared__ float As[16][68];
    __shared__ float Bs[16][68];
    __shared__ float sSc[64], sSh[64];
    int t = threadIdx.x;
    int tx = t & 15, ty = t >> 4;
    int row0 = blockIdx.y * 64, col0 = blockIdx.x * 64;
    if (pst && t < K) {
        float mean = pst[t] * pInvM;
        float var = pst[K + t] * pInvM - mean * mean;
        float wv = rsqrtf(var + EPSV) * pg[t];
        sSc[t] = wv;
        sSh[t] = pb[t] - mean * wv;
    }
    if (pst) __syncthreads();
    float acc[4][4] = {};
    for (int k0 = 0; k0 < K; k0 += 16) {
#pragma unroll
        for (int p = 0; p < 4; ++p) {
            int i = t + 256 * p;
            int m = i >> 4, k = i & 15;
            int gm = row0 + m, gk = k0 + k;
            float av = 0.f;
            if (gm < M && gk < K) {
                av = A[(size_t)gm * K + gk];
                if (pst) {
                    av = fmaf(av, sSc[gk], sSh[gk]);
                    av = fmaxf(av, 0.f);
                }
            }
            As[k][m] = av;
        }
#pragma unroll
        for (int p = 0; p < 4; ++p) {
            int i = t + 256 * p;
            if (TRANSB) {
                int k = i & 15, n = i >> 4;
                int gn = col0 + n, gk = k0 + k;
                Bs[k][n] = (gn < Nc && gk < K) ? Bm[(size_t)gn * K + gk] : 0.f;
            } else {
                int n = i & 63, k = i >> 6;
                int gn = col0 + n, gk = k0 + k;
                Bs[k][n] = (gn < Nc && gk < K) ? Bm[(size_t)gk * Nc + gn] : 0.f;
            }
        }
        __syncthreads();
#pragma unroll
        for (int kk = 0; kk < 16; ++kk) {
            float4 a4 = *(const float4*)&As[kk][ty * 4];
            float4 b4 = *(const float4*)&Bs[kk][tx * 4];
            float av[4] = {a4.x, a4.y, a4.z, a4.w};
            float bv[4] = {b4.x, b4.y, b4.z, b4.w};
#pragma unroll
            for (int i = 0; i < 4; ++i)
#pragma unroll
                for (int j = 0; j < 4; ++j) acc[i][j] = fmaf(av[i], bv[j], acc[i][j]);
        }
        __syncthreads();
    }
    float cs[4] = {}, css[4] = {};
#pragma unroll
    for (int i = 0; i < 4; ++i) {
        int r = row0 + ty * 4 + i;
        if (r >= M) continue;
#pragma unroll
        for (int j = 0; j < 4; ++j) {
            int c = col0 + tx * 4 + j;
            if (c >= Nc) continue;
            float v = acc[i][j];
            if (BIAS) v += bias[c];
            Cm[(size_t)r * Nc + c] = v;
            cs[j] += v;
            css[j] += v * v;
        }
    }
    if (ost) {
        float* sc = &As[0][0];  // 128 floats scratch
        if (t < 128) sc[t] = 0.f;
        __syncthreads();
#pragma unroll
        for (int j = 0; j < 4; ++j) {
            atomicAdd(&sc[tx * 4 + j], cs[j]);
            atomicAdd(&sc[64 + tx * 4 + j], css[j]);
        }
        __syncthreads();
        if (t < Nc) atomicAdd(&ost[t], sc[t]);
        else if (t >= 64 && t - 64 < Nc) atomicAdd(&ost[Nc + t - 64], sc[t]);
    }
}

// ---------------------------------------------------------------------------
// Pre-split fp16 MFMA GEMM. A: Ah/Al [M][K] fp16; B: Bh/Bl [N][K] fp16.
#define EPI_F32 0
#define EPI_QK 1
#define EPI_VT 2

template <int TM>
__device__ __forceinline__ void gemm_h_body(
    const _Float16* __restrict__ Ah, const _Float16* __restrict__ Al,
    const _Float16* __restrict__ Bh, const _Float16* __restrict__ Bl,
    const float* __restrict__ bias, float* __restrict__ Cf,
    _Float16* __restrict__ Ch, _Float16* __restrict__ Cl,
    int Nc, int K, int row0, int col0, int mode, float scl,
    float* __restrict__ ost,
    _Float16* sAh, _Float16* sAl, _Float16* sBh, _Float16* sBl) {
    int t = threadIdx.x, w = t >> 6, lane = t & 63;
    int col = lane & 15, quad = lane >> 4;
    const int m0w = (TM == 128) ? (w & 1) * 64 : 0;
    const int n0w = (TM == 128) ? (w >> 1) * 32 : w * 16;
    constexpr int NT = (TM == 128) ? 2 : 1;
    constexpr int AC = TM / 64;
    f32x4 acc[4][NT];
#pragma unroll
    for (int i = 0; i < 4; ++i)
#pragma unroll
        for (int j = 0; j < NT; ++j) acc[i][j] = (f32x4){0.f, 0.f, 0.f, 0.f};

    for (int k0 = 0; k0 < K; k0 += 32) {
        f16x8 rah[AC], ral[AC], rbh, rbl;
#pragma unroll
        for (int i = 0; i < AC; ++i) {
            int idx = t + 256 * i;
            int r = idx >> 2, off = (idx & 3) * 8;
            rah[i] = *(const f16x8*)(Ah + (size_t)(row0 + r) * K + k0 + off);
            ral[i] = *(const f16x8*)(Al + (size_t)(row0 + r) * K + k0 + off);
        }
        {
            int r = t >> 2, off = (t & 3) * 8;
            rbh = *(const f16x8*)(Bh + (size_t)(col0 + r) * K + k0 + off);
            rbl = *(const f16x8*)(Bl + (size_t)(col0 + r) * K + k0 + off);
        }
        __syncthreads();
#pragma unroll
        for (int i = 0; i < AC; ++i) {
            int idx = t + 256 * i;
            int r = idx >> 2, off = (idx & 3) * 8;
            *(f16x8*)&sAh[r * 40 + off] = rah[i];
            *(f16x8*)&sAl[r * 40 + off] = ral[i];
        }
        {
            int r = t >> 2, off = (t & 3) * 8;
            *(f16x8*)&sBh[r * 40 + off] = rbh;
            *(f16x8*)&sBl[r * 40 + off] = rbl;
        }
        __syncthreads();
        f16x8 fah[4], fal[4], fbh[NT], fbl[NT];
#pragma unroll
        for (int i = 0; i < 4; ++i) {
            fah[i] = *(const f16x8*)&sAh[(m0w + i * 16 + col) * 40 + quad * 8];
            fal[i] = *(const f16x8*)&sAl[(m0w + i * 16 + col) * 40 + quad * 8];
        }
#pragma unroll
        for (int j = 0; j < NT; ++j) {
            fbh[j] = *(const f16x8*)&sBh[(n0w + j * 16 + col) * 40 + quad * 8];
            fbl[j] = *(const f16x8*)&sBl[(n0w + j * 16 + col) * 40 + quad * 8];
        }
#pragma unroll
        for (int i = 0; i < 4; ++i)
#pragma unroll
            for (int j = 0; j < NT; ++j) {
                acc[i][j] = __builtin_amdgcn_mfma_f32_16x16x32_f16(fah[i], fbh[j], acc[i][j], 0, 0, 0);
                acc[i][j] = __builtin_amdgcn_mfma_f32_16x16x32_f16(fah[i], fbl[j], acc[i][j], 0, 0, 0);
                acc[i][j] = __builtin_amdgcn_mfma_f32_16x16x32_f16(fal[i], fbh[j], acc[i][j], 0, 0, 0);
            }
    }
    float s = 0.f, ss = 0.f;
#pragma unroll
    for (int i = 0; i < 4; ++i)
#pragma unroll
        for (int j = 0; j < NT; ++j) {
            int n = col0 + n0w + j * 16 + col;
            int mb = row0 + m0w + i * 16 + quad * 4;
            if (mode == EPI_F32) {
                float bv = bias ? bias[n] : 0.f;
#pragma unroll
                for (int r = 0; r < 4; ++r) {
                    float v = acc[i][j][r] + bv;
                    Cf[(size_t)(mb + r) * Nc + n] = v;
                    s += v;
                    ss += v * v;
                }
            } else if (mode == EPI_QK) {
#pragma unroll
                for (int r = 0; r < 4; ++r) {
                    hl16 sp = split2(acc[i][j][r] * scl);
                    Ch[(size_t)(mb + r) * Nc + n] = sp.h;
                    Cl[(size_t)(mb + r) * Nc + n] = sp.l;
                }
            } else {  // EPI_VT: [b][h][d][token]
                int b = mb >> 11, token = mb & 2047;
                int h = n >> 5, d = n & 31;
                f16x4 h4, l4;
#pragma unroll
                for (int r = 0; r < 4; ++r) {
                    hl16 sp = split2(acc[i][j][r]);
                    h4[r] = sp.h;
                    l4[r] = sp.l;
                }
                size_t dst = ((size_t)(b * HH + h) * DH + d) * NN + token;
                *(f16x4*)&Ch[dst] = h4;
                *(f16x4*)&Cl[dst] = l4;
            }
        }
    if (ost && mode == EPI_F32 && TM == 64) {
        s += __shfl_xor(s, 16);
        s += __shfl_xor(s, 32);
        ss += __shfl_xor(ss, 16);
        ss += __shfl_xor(ss, 32);
        if (quad == 0) {
            int n = col0 + n0w + col;
            atomicAdd(&ost[n], s);
            atomicAdd(&ost[Nc + n], ss);
        }
    }
}

template <int TM>
__global__ __launch_bounds__(256) void gemm_h_k(const _Float16* __restrict__ Ah,
                                                const _Float16* __restrict__ Al,
                                                const _Float16* __restrict__ Bh,
                                                const _Float16* __restrict__ Bl,
                                                const float* __restrict__ bias,
                                                float* __restrict__ Cf, int Nc, int K,
                                                float* __restrict__ ost) {
    __shared__ _Float16 sAh[TM * 40], sAl[TM * 40], sBh[64 * 40], sBl[64 * 40];
    gemm_h_body<TM>(Ah, Al, Bh, Bl, bias, Cf, nullptr, nullptr, Nc, K,
                    blockIdx.y * TM, blockIdx.x * 64, EPI_F32, 1.f, ost,
                    sAh, sAl, sBh, sBl);
}

// Fused QKV: blockIdx.x in [0,12): mat = x>>2, col block = x&3.
// Q scale folds 1/sqrt(dh) AND log2(e) (softmax uses exp2).
__global__ __launch_bounds__(256) void qkv_h_k(const _Float16* __restrict__ Xh,
                                               const _Float16* __restrict__ Xl,
                                               const _Float16* __restrict__ wt, int layer,
                                               _Float16* Qh, _Float16* Ql,
                                               _Float16* Kh, _Float16* Kl,
                                               _Float16* Vh, _Float16* Vl) {
    __shared__ _Float16 sAh[128 * 40], sAl[128 * 40], sBh[64 * 40], sBl[64 * 40];
    int mat = blockIdx.x >> 2;
    int slot = (layer * 4 + mat) * 2;
    const _Float16* Bh = wt + (size_t)slot * WT_SLOT;
    const _Float16* Bl = wt + (size_t)(slot + 1) * WT_SLOT;
    _Float16* Ch = mat == 0 ? Qh : mat == 1 ? Kh : Vh;
    _Float16* Cl = mat == 0 ? Ql : mat == 1 ? Kl : Vl;
    int mode = (mat == 2) ? EPI_VT : EPI_QK;
    float scl = (mat == 0) ? 0.25501654859214384f : 1.f;  // 1/sqrt(32)*log2(e)
    gemm_h_body<128>(Xh, Xl, Bh, Bl, nullptr, nullptr, Ch, Cl, CC, CC,
                     blockIdx.y * 128, (blockIdx.x & 3) * 64, mode, scl, nullptr,
                     sAh, sAl, sBh, sBl);
}

// ---------------------------------------------------------------------------
// Attention v4.1: 64-key tiles, pre-split fp16, 64 q/block (16/wave).
__global__ __launch_bounds__(256) void attn4_k(_Float16* QOh, _Float16* QOl,
                                               const _Float16* __restrict__ Kh,
                                               const _Float16* __restrict__ Kl,
                                               const _Float16* __restrict__ Vh,
                                               const _Float16* __restrict__ Vl) {
    __shared__ _Float16 sKh[64 * 40], sKl[64 * 40];   // [key][d]
    __shared__ _Float16 sVh[32 * 72], sVl[32 * 72];   // [d][key]
    __shared__ _Float16 sPh[4][16 * 72], sPl[4][16 * 72];  // per-wave [q][key]
    int t = threadIdx.x, w = t >> 6, lane = t & 63;
    int col = lane & 15, quad = lane >> 4;
    int bh = blockIdx.y, b = bh >> 3, h = bh & 7;
    int qbase = blockIdx.x * 64 + w * 16;

    size_t qoff = ((size_t)(b * NN + qbase + col)) * CC + h * DH + quad * 8;
    f16x8 qh = *(const f16x8*)(QOh + qoff);
    f16x8 ql = *(const f16x8*)(QOl + qoff);

    f32x4 o0 = {0.f, 0.f, 0.f, 0.f}, o1 = {0.f, 0.f, 0.f, 0.f};
    float mrun = -1e30f, lsum = 0.f;

    // hoisted LDS base pointers
    const _Float16* fKh = &sKh[col * 40 + quad * 8];
    const _Float16* fKl = &sKl[col * 40 + quad * 8];
    const _Float16* fVh0 = &sVh[col * 72 + quad * 8];
    const _Float16* fVl0 = &sVl[col * 72 + quad * 8];
    const _Float16* fVh1 = &sVh[(16 + col) * 72 + quad * 8];
    const _Float16* fVl1 = &sVl[(16 + col) * 72 + quad * 8];
    _Float16* wPh = &sPh[w][col * 72 + quad * 4];
    _Float16* wPl = &sPl[w][col * 72 + quad * 4];
    const _Float16* rPh = &sPh[w][col * 72 + quad * 8];
    const _Float16* rPl = &sPl[w][col * 72 + quad * 8];

    // staging: t<128 -> hi planes, t>=128 -> lo planes. 32B per thread per tensor.
    int pidx = t & 127;
    int krow = pidx >> 1, koff = (pidx & 1) * 16;   // K: [key][d], 64x32 halves
    int vrow = pidx >> 2, voff = (pidx & 3) * 16;   // V: [d][key], 32x64 halves
    const _Float16* kg = (t < 128 ? Kh : Kl) + (size_t)b * NN * CC + h * DH;
    const _Float16* vg = (t < 128 ? Vh : Vl) + ((size_t)(b * HH + h) * DH + vrow) * NN;
    _Float16* dK = (t < 128 ? sKh : sKl) + krow * 40 + koff;
    _Float16* dV = (t < 128 ? sVh : sVl) + vrow * 72 + voff;

    for (int k0 = 0; k0 < NN; k0 += 64) {
        const _Float16* kp = kg + (size_t)(k0 + krow) * CC + koff;
        f16x8 rk0 = *(const f16x8*)kp;
        f16x8 rk1 = *(const f16x8*)(kp + 8);
        const _Float16* vp = vg + k0 + voff;
        f16x8 rv0 = *(const f16x8*)vp;
        f16x8 rv1 = *(const f16x8*)(vp + 8);
        __syncthreads();  // previous tile fully consumed
        *(f16x8*)dK = rk0;
        *(f16x8*)(dK + 8) = rk1;
        *(f16x8*)dV = rv0;
        *(f16x8*)(dV + 8) = rv1;
        __syncthreads();

        // ---- QK^T (S^T = K·Q^T): 4 key subtiles ----
        f32x4 s[4];
#pragma unroll
        for (int kt = 0; kt < 4; ++kt) {
            f16x8 ka = *(const f16x8*)(fKh + kt * 16 * 40);
            f16x8 kb = *(const f16x8*)(fKl + kt * 16 * 40);
            f32x4 z = {0.f, 0.f, 0.f, 0.f};
            z = __builtin_amdgcn_mfma_f32_16x16x32_f16(ka, qh, z, 0, 0, 0);
            z = __builtin_amdgcn_mfma_f32_16x16x32_f16(ka, ql, z, 0, 0, 0);
            z = __builtin_amdgcn_mfma_f32_16x16x32_f16(kb, qh, z, 0, 0, 0);
            s[kt] = z;
        }

        // ---- online softmax over 64 keys ----
        float tm = -1e30f;
#pragma unroll
        for (int kt = 0; kt < 4; ++kt)
#pragma unroll
            for (int r = 0; r < 4; ++r) tm = fmaxf(tm, s[kt][r]);
        tm = fmaxf(tm, __shfl_xor(tm, 16));
        tm = fmaxf(tm, __shfl_xor(tm, 32));
        float nm = fmaxf(mrun, tm);
        float alpha = __builtin_amdgcn_exp2f(mrun - nm);
        float p[16], rs = 0.f;
#pragma unroll
        for (int kt = 0; kt < 4; ++kt)
#pragma unroll
            for (int r = 0; r < 4; ++r) {
                float pv = __builtin_amdgcn_exp2f(s[kt][r] - nm);
                p[kt * 4 + r] = pv;
                rs += pv;
            }
        rs += __shfl_xor(rs, 16);
        rs += __shfl_xor(rs, 32);
        lsum = lsum * alpha + rs;
        mrun = nm;
        o0.x *= alpha; o0.y *= alpha; o0.z *= alpha; o0.w *= alpha;
        o1.x *= alpha; o1.y *= alpha; o1.z *= alpha; o1.w *= alpha;

        // ---- P split + per-wave LDS transpose ([q][key 0..63]) ----
#pragma unroll
        for (int kt = 0; kt < 4; ++kt) {
            f16x4 h4, l4;
#pragma unroll
            for (int r = 0; r < 4; ++r) {
                hl16 sp = split2(p[kt * 4 + r]);
                h4[r] = sp.h;
                l4[r] = sp.l;
            }
            *(f16x4*)(wPh + kt * 16) = h4;
            *(f16x4*)(wPl + kt * 16) = l4;
        }
        __asm__ volatile("s_waitcnt lgkmcnt(0)" ::: "memory");
        f16x8 pH[2], pL[2];
#pragma unroll
        for (int c = 0; c < 2; ++c) {
            pH[c] = *(const f16x8*)(rPh + c * 32);
            pL[c] = *(const f16x8*)(rPl + c * 32);
        }

        // ---- PV: O^T += V^T · P^T (2 key chunks × 2 d-halves) ----
#pragma unroll
        for (int c = 0; c < 2; ++c) {
            f16x8 va = *(const f16x8*)(fVh0 + c * 32);
            f16x8 vb = *(const f16x8*)(fVl0 + c * 32);
            o0 = __builtin_amdgcn_mfma_f32_16x16x32_f16(va, pH[c], o0, 0, 0, 0);
            o0 = __builtin_amdgcn_mfma_f32_16x16x32_f16(va, pL[c], o0, 0, 0, 0);
            o0 = __builtin_amdgcn_mfma_f32_16x16x32_f16(vb, pH[c], o0, 0, 0, 0);
            f16x8 vc = *(const f16x8*)(fVh1 + c * 32);
            f16x8 vd = *(const f16x8*)(fVl1 + c * 32);
            o1 = __builtin_amdgcn_mfma_f32_16x16x32_f16(vc, pH[c], o1, 0, 0, 0);
            o1 = __builtin_amdgcn_mfma_f32_16x16x32_f16(vc, pL[c], o1, 0, 0, 0);
            o1 = __builtin_amdgcn_mfma_f32_16x16x32_f16(vd, pH[c], o1, 0, 0, 0);
        }
    }

    // epilogue: O^T layout col=q, row=d. Write split O into Q buffer (own tokens).
    float inv = 1.f / lsum;
    f32x4 oo[2] = {o0, o1};
#pragma unroll
    for (int dh = 0; dh < 2; ++dh) {
        f16x4 h4, l4;
#pragma unroll
        for (int r = 0; r < 4; ++r) {
            hl16 s = split2(oo[dh][r] * inv);
            h4[r] = s.h;
            l4[r] = s.l;
        }
        size_t dsti = ((size_t)(b * NN + qbase + col)) * CC + h * DH + dh * 16 + quad * 4;
        *(f16x4*)&QOh[dsti] = h4;
        *(f16x4*)&QOl[dsti] = l4;
    }
}

// ---------------------------------------------------------------------------
__global__ __launch_bounds__(256) void add_ln_k(float* __restrict__ X,
                                                const float* __restrict__ P,
                                                const float* __restrict__ g,
                                                const float* __restrict__ bta,
                                                _Float16* __restrict__ Xh,
                                                _Float16* __restrict__ Xl) {
    int wave = threadIdx.x >> 6, lane = threadIdx.x & 63;
    size_t row = (size_t)blockIdx.x * 4 + wave;
    size_t base = row * CC + lane * 4;
    float4 x = *(float4*)(X + base);
    float4 p = *(const float4*)(P + base);
    x.x += p.x; x.y += p.y; x.z += p.z; x.w += p.w;
    float sum = x.x + x.y + x.z + x.w;
    float ss = x.x * x.x + x.y * x.y + x.z * x.z + x.w * x.w;
#pragma unroll
    for (int off = 32; off; off >>= 1) {
        sum += __shfl_down(sum, off);
        ss += __shfl_down(ss, off);
    }
    sum = __shfl(sum, 0);
    ss = __shfl(ss, 0);
    float mean = sum * (1.f / 256.f);
    float var = ss * (1.f / 256.f) - mean * mean;
    float wn = rsqrtf(var + EPSV);
    float4 gg = *(const float4*)(g + lane * 4);
    float4 bb = *(const float4*)(bta + lane * 4);
    x.x = (x.x - mean) * wn * gg.x + bb.x;
    x.y = (x.y - mean) * wn * gg.y + bb.y;
    x.z = (x.z - mean) * wn * gg.z + bb.z;
    x.w = (x.w - mean) * wn * gg.w + bb.w;
    *(float4*)(X + base) = x;
    f16x4 h4, l4;
    float xv[4] = {x.x, x.y, x.z, x.w};
#pragma unroll
    for (int j = 0; j < 4; ++j) {
        hl16 s = split2(xv[j]);
        h4[j] = s.h;
        l4[j] = s.l;
    }
    *(f16x4*)&Xh[base] = h4;
    *(f16x4*)&Xl[base] = l4;
}

// ---------------------------------------------------------------------------
// Conv-path BN apply (from raw sums) + LeakyReLU + split to fp16 hi/lo.
__global__ __launch_bounds__(256) void applyc_k(const float* __restrict__ in,
                                                _Float16* __restrict__ oh,
                                                _Float16* __restrict__ ol,
                                                const float* __restrict__ st,
                                                const float* __restrict__ gam,
                                                const float* __restrict__ bet,
                                                int total, int Cc, float invM) {
    int i = blockIdx.x * 256 + threadIdx.x;
    if (i >= total) return;
    int c = i % Cc;
    float mean = st[c] * invM;
    float var = st[Cc + c] * invM - mean * mean;
    float sc = rsqrtf(var + EPSV) * gam[c];
    float v = fmaf(in[i] - mean, sc, bet[c]);
    v = v > 0.f ? v : 0.2f * v;
    hl16 s = split2(v);
    oh[i] = s.h;
    ol[i] = s.l;
}

// ---------------------------------------------------------------------------
// Fused: BN3(raw sums)+ReLU -> argmax -> ball query -> gather grouped coords.
__global__ __launch_bounds__(64) void select_k(const float* __restrict__ H3,
                                               const float* __restrict__ pts,
                                               const float* __restrict__ st,
                                               const float* __restrict__ gam,
                                               const float* __restrict__ bet,
                                               float* __restrict__ G0) {
    int bs = blockIdx.x;
    int b = bs >> 4, ch = bs & 15;
    int lane = threadIdx.x;
    float mean = st[ch] * INV_MF;
    float var = st[16 + ch] * INV_MF - mean * mean;
    float sc = rsqrtf(var + EPSV) * gam[ch];
    float sh = bet[ch] - mean * sc;
    float best = -1e30f;
    int bn = 0;
    for (int n = lane; n < NN; n += 64) {
        float v = fmaf(H3[((size_t)(b * NN + n)) * 16 + ch], sc, sh);
        v = fmaxf(v, 0.f);
        if (v > best) { best = v; bn = n; }
    }
#pragma unroll
    for (int off = 32; off; off >>= 1) {
        float ov = __shfl_xor(best, off);
        int on = __shfl_xor(bn, off);
        if (ov > best || (ov == best && on < bn)) { best = ov; bn = on; }
    }
    const float* px = pts + (size_t)b * 3 * NN;
    float qx = px[bn], qy = px[NN + bn], qz = px[2 * NN + bn];
    float qq = (qx * qx + qy * qy) + qz * qz;
    __shared__ int sgi[NSAMPLE];
    const float R2 = 0.09f;
    int cnt = 0;
    for (int base = 0; base < NN && cnt < NSAMPLE; base += 64) {
        int n = base + lane;
        float x = px[n], y = px[NN + n], z = px[2 * NN + n];
        float pp = (x * x + y * y) + z * z;
        float dot = (qx * x + qy * y) + qz * z;
        float sqd = (qq + pp) - 2.f * dot;
        bool ok = !(sqd > R2);
        unsigned long long mk = __ballot(ok);
        int pos = cnt + (int)__popcll(mk & ((1ull << lane) - 1ull));
        if (ok && pos < NSAMPLE) sgi[pos] = n;
        cnt += (int)__popcll(mk);
    }
    __syncthreads();
    int g0 = sgi[0];
    if (lane >= cnt && lane < NSAMPLE) sgi[lane] = g0;
    __syncthreads();
    for (int e = lane; e < KK * 3; e += 64) {
        int k = e / 3, d = e % 3;
        int src = (k == 0) ? bn : sgi[k - 1];
        G0[((size_t)bs * KK + k) * 3 + d] = px[d * NN + src];
    }
}

// ---------------------------------------------------------------------------
// Fused BN(C3, raw sums)+LeakyReLU+max over k.
__global__ __launch_bounds__(256) void maxpool_k(const float* __restrict__ G3,
                                                 const float* __restrict__ st,
                                                 const float* __restrict__ gam,
                                                 const float* __restrict__ bet,
                                                 float* __restrict__ out) {
    int i = blockIdx.x * 256 + threadIdx.x;
    if (i >= BB * 512 * SS) return;
    int o = i & 511;
    int s = (i >> 9) & 15;
    int b = i >> 13;
    float mean = st[o] * INV_MG;
    float var = st[512 + o] * INV_MG - mean * mean;
    float sc = rsqrtf(var + EPSV) * gam[o];
    float sh = bet[o] - mean * sc;
    const float* p = G3 + ((size_t)(b * SS + s) * KK) * 512 + o;
    float mx = -1e30f;
#pragma unroll
    for (int k = 0; k < KK; ++k) {
        float v = fmaf(p[(size_t)k * 512], sc, sh);
        v = v > 0.f ? v : 0.2f * v;
        mx = fmaxf(mx, v);
    }
    out[((size_t)(b * 512 + o)) * SS + s] = mx;
}

// ---------------------------------------------------------------------------
extern "C" void kernel_launch(void* const* d_in, const int* in_sizes, int n_in,
                              void* d_out, int out_size, void* d_ws, size_t ws_size,
                              hipStream_t stream) {
    const float* hoch = (const float*)d_in[0];
    const float* pts = (const float*)d_in[1];
    const float* Wq = (const float*)d_in[2];
    const float* Wk = (const float*)d_in[3];
    const float* Wv = (const float*)d_in[4];
    const float* Wo = (const float*)d_in[5];
    const float* ln_g = (const float*)d_in[6];
    const float* ln_b = (const float*)d_in[7];
    const float* fg_w1 = (const float*)d_in[8];
    const float* fg_b1 = (const float*)d_in[9];
    const float* fg_w2 = (const float*)d_in[10];
    const float* fg_b2 = (const float*)d_in[11];
    const float* fg_w3 = (const float*)d_in[12];
    const float* fg_b3 = (const float*)d_in[13];
    const float* fg_g1 = (const float*)d_in[14];
    const float* fg_be1 = (const float*)d_in[15];
    const float* fg_g2 = (const float*)d_in[16];
    const float* fg_be2 = (const float*)d_in[17];
    const float* fg_g3 = (const float*)d_in[18];
    const float* fg_be3 = (const float*)d_in[19];
    const float* cw1 = (const float*)d_in[20];
    const float* cw2 = (const float*)d_in[21];
    const float* cw3 = (const float*)d_in[22];
    const float* cg1 = (const float*)d_in[23];
    const float* cb1 = (const float*)d_in[24];
    const float* cg2 = (const float*)d_in[25];
    const float* cb2 = (const float*)d_in[26];
    const float* cg3 = (const float*)d_in[27];
    const float* cb3 = (const float*)d_in[28];
    float* out = (float*)d_out;

    float* ws = (float*)d_ws;
    const size_t M1 = (size_t)BB * NN * CC;  // 2,097,152
    float* X = ws;
    float* bA = ws + M1;
    float* bB = ws + 2 * M1;
    float* bC = ws + 3 * M1;
    _Float16* hb = (_Float16*)(ws + 4 * M1);
    _Float16* Xh = hb;
    _Float16* Xl = hb + M1;
    _Float16* Qh = hb + 2 * M1;  // also O (attn writes split O back here)
    _Float16* Ql = hb + 3 * M1;
    _Float16* Kh = hb + 4 * M1;  // also conv activations post-transformer
    _Float16* Kl = hb + 5 * M1;
    _Float16* Vh = hb + 6 * M1;
    _Float16* Vl = hb + 7 * M1;
    _Float16* wt = hb + 8 * M1;  // 1,376,256 halves
    float* sm = ws + 4 * M1 + (9 * M1) / 2;
    float* st1 = sm;
    float* st2 = sm + 1024;
    float* st3 = sm + 2048;
    float* st4 = sm + 3072;
    float* st5 = sm + 4096;
    float* st6 = sm + 5120;
    float* G0 = sm + 8192;  // 6336

    prep_split_k<<<2688, 256, 0, stream>>>(Wq, Wk, Wv, Wo, fg_w1, cw2, cw3, wt, sm);
    transpose_split_k<<<dim3(NN / 32, CC / 32, BB), dim3(32, 8), 0, stream>>>(hoch, X, Xh, Xl);

    const int Mrows = BB * NN;  // 8192
    for (int l = 0; l < LL; ++l) {
        qkv_h_k<<<dim3(12, Mrows / 128), 256, 0, stream>>>(Xh, Xl, wt, l, Qh, Ql, Kh, Kl, Vh, Vl);
        attn4_k<<<dim3(NN / 64, BB * HH), 256, 0, stream>>>(Qh, Ql, Kh, Kl, Vh, Vl);
        int slot = (l * 4 + 3) * 2;
        gemm_h_k<128><<<dim3(CC / 64, Mrows / 128), 256, 0, stream>>>(
            Qh, Ql, wt + (size_t)slot * WT_SLOT, wt + (size_t)(slot + 1) * WT_SLOT,
            nullptr, bA, CC, CC, nullptr);
        add_ln_k<<<Mrows / 4, 256, 0, stream>>>(X, bA, ln_g + l * CC, ln_b + l * CC, Xh, Xl);
    }

    // fg head: 256 -> 64 -> 32 -> 16; stats fused in epilogues, BN fused forward
    gemm_h_k<64><<<dim3(1, Mrows / 64), 256, 0, stream>>>(Xh, Xl, wt + FG1H_OFF, wt + FG1L_OFF, fg_b1, bA, 64, 256, st1);
    gemm_k<true, true><<<dim3(1, Mrows / 64), 256, 0, stream>>>(bA, fg_w2, fg_b2, bB, Mrows, 32, 64,
                                                                st1, fg_g1, fg_be1, INV_MF, st2);
    gemm_k<true, true><<<dim3(1, Mrows / 64), 256, 0, stream>>>(bB, fg_w3, fg_b3, bC, Mrows, 16, 32,
                                                                st2, fg_g2, fg_be2, INV_MF, st3);

    // selection + grouping (applies BN3+ReLU internally)
    select_k<<<BB * SS, 64, 0, stream>>>(bC, pts, st3, fg_g3, fg_be3, G0);

    // conv stack: 3 -> 64 -> 256 -> 512
    const int Mg = BB * SS * KK;  // 2112 = 33*64
    gemm_k<true, false><<<dim3(1, Mg / 64), 256, 0, stream>>>(G0, cw1, nullptr, bA, Mg, 64, 3,
                                                              nullptr, nullptr, nullptr, 0.f, st4);
    applyc_k<<<(Mg * 64 + 255) / 256, 256, 0, stream>>>(bA, Kh, Kl, st4, cg1, cb1, Mg * 64, 64, INV_MG);
    gemm_h_k<64><<<dim3(4, Mg / 64), 256, 0, stream>>>(Kh, Kl, wt + CW2H_OFF, wt + CW2L_OFF, nullptr, bB, 256, 64, st5);
    applyc_k<<<(Mg * 256 + 255) / 256, 256, 0, stream>>>(bB, Kh, Kl, st5, cg2, cb2, Mg * 256, 256, INV_MG);
    gemm_h_k<64><<<dim3(8, Mg / 64), 256, 0, stream>>>(Kh, Kl, wt + CW3H_OFF, wt + CW3L_OFF, nullptr, bC, 512, 256, st6);

    // fused BN(C3)+LeakyReLU+maxpool
    maxpool_k<<<(BB * 512 * SS + 255) / 256, 256, 0, stream>>>(bC, st6, cg3, cb3, out);

    (void)in_sizes; (void)n_in; (void)out_size; (void)ws_size;
}

// Round 13
// 413.680 us; speedup vs baseline: 1.1868x; 1.1383x over previous
//
#include <hip/hip_runtime.h>
#include <hip/hip_bf16.h>
#include <math.h>

// Problem constants
#define BB 4
#define NN 2048
#define CC 256
#define HH 8
#define DH 32
#define LL 2
#define SS 16
#define KK 33
#define NSAMPLE 32
#define EPSV 1e-5f

typedef _Float16 f16x8 __attribute__((ext_vector_type(8)));
typedef _Float16 f16x4 __attribute__((ext_vector_type(4)));
typedef float f32x4 __attribute__((ext_vector_type(4)));

struct hl16 { _Float16 h, l; };
__device__ __forceinline__ hl16 split2(float v) {
    hl16 r;
    r.h = (_Float16)v;
    r.l = (_Float16)(v - (float)r.h);
    return r;
}

#define INV_MF (1.f / 8192.f)
#define INV_MG (1.f / 2112.f)

// Pre-split weight table offsets (in halves)
#define WT_SLOT 65536
#define FG1H_OFF 1048576
#define FG1L_OFF (FG1H_OFF + 16384)
#define CW2H_OFF (FG1H_OFF + 32768)
#define CW2L_OFF (FG1H_OFF + 49152)
#define CW3H_OFF (FG1H_OFF + 65536)
#define CW3L_OFF (CW3H_OFF + 131072)

// ---------------------------------------------------------------------------
// One-time: zero stats regions + split all MFMA-path weights to fp16 hi/lo.
__global__ __launch_bounds__(256) void prep_split_k(
    const float* __restrict__ Wq, const float* __restrict__ Wk,
    const float* __restrict__ Wv, const float* __restrict__ Wo,
    const float* __restrict__ fgw1, const float* __restrict__ cw2,
    const float* __restrict__ cw3, _Float16* __restrict__ wt,
    float* __restrict__ stats0) {
    int e = blockIdx.x * 256 + threadIdx.x;
    if (e < 6144) stats0[e] = 0.f;
    if (e < 524288) {
        int slot = e >> 16;  // l*4 + mat
        int l = slot >> 2, mat = slot & 3;
        int r = e & 65535;
        int n = r >> 8, k = r & 255;
        const float* W = mat == 0 ? Wq : mat == 1 ? Wk : mat == 2 ? Wv : Wo;
        hl16 s = split2(W[(size_t)l * 65536 + k * 256 + n]);
        wt[(size_t)(2 * slot) * WT_SLOT + n * 256 + k] = s.h;
        wt[(size_t)(2 * slot + 1) * WT_SLOT + n * 256 + k] = s.l;
    } else if (e < 524288 + 16384) {
        int r = e - 524288;
        hl16 s = split2(fgw1[r]);
        wt[FG1H_OFF + r] = s.h;
        wt[FG1L_OFF + r] = s.l;
    } else if (e < 524288 + 32768) {
        int r = e - (524288 + 16384);
        hl16 s = split2(cw2[r]);
        wt[CW2H_OFF + r] = s.h;
        wt[CW2L_OFF + r] = s.l;
    } else if (e < 524288 + 32768 + 131072) {
        int r = e - (524288 + 32768);
        hl16 s = split2(cw3[r]);
        wt[CW3H_OFF + r] = s.h;
        wt[CW3L_OFF + r] = s.l;
    }
}

// ---------------------------------------------------------------------------
__global__ __launch_bounds__(256) void transpose_split_k(const float* __restrict__ in,
                                                         float* __restrict__ out,
                                                         _Float16* __restrict__ oh,
                                                         _Float16* __restrict__ ol) {
    __shared__ float tls[32][33];
    int n0 = blockIdx.x * 32, c0 = blockIdx.y * 32, b = blockIdx.z;
    const float* ip = in + (size_t)b * CC * NN;
    size_t ob = (size_t)b * NN * CC;
    int tx = threadIdx.x, ty = threadIdx.y;
#pragma unroll
    for (int i = 0; i < 4; ++i)
        tls[ty + i * 8][tx] = ip[(size_t)(c0 + ty + i * 8) * NN + n0 + tx];
    __syncthreads();
#pragma unroll
    for (int i = 0; i < 4; ++i) {
        size_t oi = ob + (size_t)(n0 + ty + i * 8) * CC + c0 + tx;
        float v = tls[tx][ty + i * 8];
        out[oi] = v;
        hl16 s = split2(v);
        oh[oi] = s.h;
        ol[oi] = s.l;
    }
}

// ---------------------------------------------------------------------------
// fp32 GEMM with optional fused input-BN+ReLU (staging) and output-stats.
template <bool TRANSB, bool BIAS>
__global__ __launch_bounds__(256) void gemm_k(const float* __restrict__ A,
                                              const float* __restrict__ Bm,
                                              const float* __restrict__ bias,
                                              float* __restrict__ Cm,
                                              int M, int Nc, int K,
                                              const float* __restrict__ pst,
                                              const float* __restrict__ pg,
                                              const float* __restrict__ pb,
                                              float pInvM,
                                              float* __restrict__ ost) {
    __shared__ float As[16][68];
    __shared__ float Bs[16][68];
    __shared__ float sSc[64], sSh[64];
    int t = threadIdx.x;
    int tx = t & 15, ty = t >> 4;
    int row0 = blockIdx.y * 64, col0 = blockIdx.x * 64;
    if (pst && t < K) {
        float mean = pst[t] * pInvM;
        float var = pst[K + t] * pInvM - mean * mean;
        float wv = rsqrtf(var + EPSV) * pg[t];
        sSc[t] = wv;
        sSh[t] = pb[t] - mean * wv;
    }
    if (pst) __syncthreads();
    float acc[4][4] = {};
    for (int k0 = 0; k0 < K; k0 += 16) {
#pragma unroll
        for (int p = 0; p < 4; ++p) {
            int i = t + 256 * p;
            int m = i >> 4, k = i & 15;
            int gm = row0 + m, gk = k0 + k;
            float av = 0.f;
            if (gm < M && gk < K) {
                av = A[(size_t)gm * K + gk];
                if (pst) {
                    av = fmaf(av, sSc[gk], sSh[gk]);
                    av = fmaxf(av, 0.f);
                }
            }
            As[k][m] = av;
        }
#pragma unroll
        for (int p = 0; p < 4; ++p) {
            int i = t + 256 * p;
            if (TRANSB) {
                int k = i & 15, n = i >> 4;
                int gn = col0 + n, gk = k0 + k;
                Bs[k][n] = (gn < Nc && gk < K) ? Bm[(size_t)gn * K + gk] : 0.f;
            } else {
                int n = i & 63, k = i >> 6;
                int gn = col0 + n, gk = k0 + k;
                Bs[k][n] = (gn < Nc && gk < K) ? Bm[(size_t)gk * Nc + gn] : 0.f;
            }
        }
        __syncthreads();
#pragma unroll
        for (int kk = 0; kk < 16; ++kk) {
            float4 a4 = *(const float4*)&As[kk][ty * 4];
            float4 b4 = *(const float4*)&Bs[kk][tx * 4];
            float av[4] = {a4.x, a4.y, a4.z, a4.w};
            float bv[4] = {b4.x, b4.y, b4.z, b4.w};
#pragma unroll
            for (int i = 0; i < 4; ++i)
#pragma unroll
                for (int j = 0; j < 4; ++j) acc[i][j] = fmaf(av[i], bv[j], acc[i][j]);
        }
        __syncthreads();
    }
    float cs[4] = {}, css[4] = {};
#pragma unroll
    for (int i = 0; i < 4; ++i) {
        int r = row0 + ty * 4 + i;
        if (r >= M) continue;
#pragma unroll
        for (int j = 0; j < 4; ++j) {
            int c = col0 + tx * 4 + j;
            if (c >= Nc) continue;
            float v = acc[i][j];
            if (BIAS) v += bias[c];
            Cm[(size_t)r * Nc + c] = v;
            cs[j] += v;
            css[j] += v * v;
        }
    }
    if (ost) {
        float* sc = &As[0][0];  // 128 floats scratch
        if (t < 128) sc[t] = 0.f;
        __syncthreads();
#pragma unroll
        for (int j = 0; j < 4; ++j) {
            atomicAdd(&sc[tx * 4 + j], cs[j]);
            atomicAdd(&sc[64 + tx * 4 + j], css[j]);
        }
        __syncthreads();
        if (t < Nc) atomicAdd(&ost[t], sc[t]);
        else if (t >= 64 && t - 64 < Nc) atomicAdd(&ost[Nc + t - 64], sc[t]);
    }
}

// ---------------------------------------------------------------------------
// Pre-split fp16 MFMA GEMM. A: Ah/Al [M][K] fp16; B: Bh/Bl [N][K] fp16.
#define EPI_F32 0
#define EPI_QK 1
#define EPI_VT 2

template <int TM>
__device__ __forceinline__ void gemm_h_body(
    const _Float16* __restrict__ Ah, const _Float16* __restrict__ Al,
    const _Float16* __restrict__ Bh, const _Float16* __restrict__ Bl,
    const float* __restrict__ bias, float* __restrict__ Cf,
    _Float16* __restrict__ Ch, _Float16* __restrict__ Cl,
    int Nc, int K, int row0, int col0, int mode, float scl,
    float* __restrict__ ost,
    _Float16* sAh, _Float16* sAl, _Float16* sBh, _Float16* sBl) {
    int t = threadIdx.x, w = t >> 6, lane = t & 63;
    int col = lane & 15, quad = lane >> 4;
    const int m0w = (TM == 128) ? (w & 1) * 64 : 0;
    const int n0w = (TM == 128) ? (w >> 1) * 32 : w * 16;
    constexpr int NT = (TM == 128) ? 2 : 1;
    constexpr int AC = TM / 64;
    f32x4 acc[4][NT];
#pragma unroll
    for (int i = 0; i < 4; ++i)
#pragma unroll
        for (int j = 0; j < NT; ++j) acc[i][j] = (f32x4){0.f, 0.f, 0.f, 0.f};

    for (int k0 = 0; k0 < K; k0 += 32) {
        f16x8 rah[AC], ral[AC], rbh, rbl;
#pragma unroll
        for (int i = 0; i < AC; ++i) {
            int idx = t + 256 * i;
            int r = idx >> 2, off = (idx & 3) * 8;
            rah[i] = *(const f16x8*)(Ah + (size_t)(row0 + r) * K + k0 + off);
            ral[i] = *(const f16x8*)(Al + (size_t)(row0 + r) * K + k0 + off);
        }
        {
            int r = t >> 2, off = (t & 3) * 8;
            rbh = *(const f16x8*)(Bh + (size_t)(col0 + r) * K + k0 + off);
            rbl = *(const f16x8*)(Bl + (size_t)(col0 + r) * K + k0 + off);
        }
        __syncthreads();
#pragma unroll
        for (int i = 0; i < AC; ++i) {
            int idx = t + 256 * i;
            int r = idx >> 2, off = (idx & 3) * 8;
            *(f16x8*)&sAh[r * 40 + off] = rah[i];
            *(f16x8*)&sAl[r * 40 + off] = ral[i];
        }
        {
            int r = t >> 2, off = (t & 3) * 8;
            *(f16x8*)&sBh[r * 40 + off] = rbh;
            *(f16x8*)&sBl[r * 40 + off] = rbl;
        }
        __syncthreads();
        f16x8 fah[4], fal[4], fbh[NT], fbl[NT];
#pragma unroll
        for (int i = 0; i < 4; ++i) {
            fah[i] = *(const f16x8*)&sAh[(m0w + i * 16 + col) * 40 + quad * 8];
            fal[i] = *(const f16x8*)&sAl[(m0w + i * 16 + col) * 40 + quad * 8];
        }
#pragma unroll
        for (int j = 0; j < NT; ++j) {
            fbh[j] = *(const f16x8*)&sBh[(n0w + j * 16 + col) * 40 + quad * 8];
            fbl[j] = *(const f16x8*)&sBl[(n0w + j * 16 + col) * 40 + quad * 8];
        }
#pragma unroll
        for (int i = 0; i < 4; ++i)
#pragma unroll
            for (int j = 0; j < NT; ++j) {
                acc[i][j] = __builtin_amdgcn_mfma_f32_16x16x32_f16(fah[i], fbh[j], acc[i][j], 0, 0, 0);
                acc[i][j] = __builtin_amdgcn_mfma_f32_16x16x32_f16(fah[i], fbl[j], acc[i][j], 0, 0, 0);
                acc[i][j] = __builtin_amdgcn_mfma_f32_16x16x32_f16(fal[i], fbh[j], acc[i][j], 0, 0, 0);
            }
    }
    float s = 0.f, ss = 0.f;
#pragma unroll
    for (int i = 0; i < 4; ++i)
#pragma unroll
        for (int j = 0; j < NT; ++j) {
            int n = col0 + n0w + j * 16 + col;
            int mb = row0 + m0w + i * 16 + quad * 4;
            if (mode == EPI_F32) {
                float bv = bias ? bias[n] : 0.f;
#pragma unroll
                for (int r = 0; r < 4; ++r) {
                    float v = acc[i][j][r] + bv;
                    Cf[(size_t)(mb + r) * Nc + n] = v;
                    s += v;
                    ss += v * v;
                }
            } else if (mode == EPI_QK) {
#pragma unroll
                for (int r = 0; r < 4; ++r) {
                    hl16 sp = split2(acc[i][j][r] * scl);
                    Ch[(size_t)(mb + r) * Nc + n] = sp.h;
                    Cl[(size_t)(mb + r) * Nc + n] = sp.l;
                }
            } else {  // EPI_VT: [b][h][d][token]
                int b = mb >> 11, token = mb & 2047;
                int h = n >> 5, d = n & 31;
                f16x4 h4, l4;
#pragma unroll
                for (int r = 0; r < 4; ++r) {
                    hl16 sp = split2(acc[i][j][r]);
                    h4[r] = sp.h;
                    l4[r] = sp.l;
                }
                size_t dst = ((size_t)(b * HH + h) * DH + d) * NN + token;
                *(f16x4*)&Ch[dst] = h4;
                *(f16x4*)&Cl[dst] = l4;
            }
        }
    if (ost && mode == EPI_F32 && TM == 64) {
        s += __shfl_xor(s, 16);
        s += __shfl_xor(s, 32);
        ss += __shfl_xor(ss, 16);
        ss += __shfl_xor(ss, 32);
        if (quad == 0) {
            int n = col0 + n0w + col;
            atomicAdd(&ost[n], s);
            atomicAdd(&ost[Nc + n], ss);
        }
    }
}

template <int TM>
__global__ __launch_bounds__(256) void gemm_h_k(const _Float16* __restrict__ Ah,
                                                const _Float16* __restrict__ Al,
                                                const _Float16* __restrict__ Bh,
                                                const _Float16* __restrict__ Bl,
                                                const float* __restrict__ bias,
                                                float* __restrict__ Cf, int Nc, int K,
                                                float* __restrict__ ost) {
    __shared__ _Float16 sAh[TM * 40], sAl[TM * 40], sBh[64 * 40], sBl[64 * 40];
    gemm_h_body<TM>(Ah, Al, Bh, Bl, bias, Cf, nullptr, nullptr, Nc, K,
                    blockIdx.y * TM, blockIdx.x * 64, EPI_F32, 1.f, ost,
                    sAh, sAl, sBh, sBl);
}

// Fused QKV: blockIdx.x in [0,12): mat = x>>2, col block = x&3.
// Q scale folds 1/sqrt(dh) AND log2(e) (softmax uses exp2).
__global__ __launch_bounds__(256) void qkv_h_k(const _Float16* __restrict__ Xh,
                                               const _Float16* __restrict__ Xl,
                                               const _Float16* __restrict__ wt, int layer,
                                               _Float16* Qh, _Float16* Ql,
                                               _Float16* Kh, _Float16* Kl,
                                               _Float16* Vh, _Float16* Vl) {
    __shared__ _Float16 sAh[128 * 40], sAl[128 * 40], sBh[64 * 40], sBl[64 * 40];
    int mat = blockIdx.x >> 2;
    int slot = (layer * 4 + mat) * 2;
    const _Float16* Bh = wt + (size_t)slot * WT_SLOT;
    const _Float16* Bl = wt + (size_t)(slot + 1) * WT_SLOT;
    _Float16* Ch = mat == 0 ? Qh : mat == 1 ? Kh : Vh;
    _Float16* Cl = mat == 0 ? Ql : mat == 1 ? Kl : Vl;
    int mode = (mat == 2) ? EPI_VT : EPI_QK;
    float scl = (mat == 0) ? 0.25501654859214384f : 1.f;  // 1/sqrt(32)*log2(e)
    gemm_h_body<128>(Xh, Xl, Bh, Bl, nullptr, nullptr, Ch, Cl, CC, CC,
                     blockIdx.y * 128, (blockIdx.x & 3) * 64, mode, scl, nullptr,
                     sAh, sAl, sBh, sBl);
}

// ---------------------------------------------------------------------------
// Attention v7: 64-key tiles, split Q/K for scores, hi-only P·V (error ~5e-4).
// LDS 23.5 KB. 64 q/block (16/wave).
__global__ __launch_bounds__(256) void attn7_k(_Float16* QOh, _Float16* QOl,
                                               const _Float16* __restrict__ Kh,
                                               const _Float16* __restrict__ Kl,
                                               const _Float16* __restrict__ Vh,
                                               const _Float16* __restrict__ Vl) {
    __shared__ _Float16 sKh[64 * 40], sKl[64 * 40];   // [key][d]
    __shared__ _Float16 sVh[32 * 72];                 // [d][key], hi only
    __shared__ _Float16 sPh[4][16 * 72];              // per-wave [q][key], hi only
    int t = threadIdx.x, w = t >> 6, lane = t & 63;
    int col = lane & 15, quad = lane >> 4;
    int bh = blockIdx.y, b = bh >> 3, h = bh & 7;
    int qbase = blockIdx.x * 64 + w * 16;

    size_t qoff = ((size_t)(b * NN + qbase + col)) * CC + h * DH + quad * 8;
    f16x8 qh = *(const f16x8*)(QOh + qoff);
    f16x8 ql = *(const f16x8*)(QOl + qoff);

    f32x4 o0 = {0.f, 0.f, 0.f, 0.f}, o1 = {0.f, 0.f, 0.f, 0.f};
    float mrun = -1e30f, lsum = 0.f;

    // hoisted LDS base pointers
    const _Float16* fKh = &sKh[col * 40 + quad * 8];
    const _Float16* fKl = &sKl[col * 40 + quad * 8];
    const _Float16* fVh0 = &sVh[col * 72 + quad * 8];
    const _Float16* fVh1 = &sVh[(16 + col) * 72 + quad * 8];
    _Float16* wPh = &sPh[w][col * 72 + quad * 4];
    const _Float16* rPh = &sPh[w][col * 72 + quad * 8];

    // staging: every thread stages 16B of Kh, Kl, Vh.
    int krow = t >> 2, koff = (t & 3) * 8;   // K: [key][d], 64x32 halves
    int vrow = t >> 3, voff = (t & 7) * 8;   // V: [d][key], 32x64 halves
    const _Float16* kgh = Kh + (size_t)b * NN * CC + h * DH;
    const _Float16* kgl = Kl + (size_t)b * NN * CC + h * DH;
    const _Float16* vgh = Vh + ((size_t)(b * HH + h) * DH + vrow) * NN;
    _Float16* dKh = sKh + krow * 40 + koff;
    _Float16* dKl = sKl + krow * 40 + koff;
    _Float16* dVh = sVh + vrow * 72 + voff;
    (void)Vl;

    for (int k0 = 0; k0 < NN; k0 += 64) {
        f16x8 rkh = *(const f16x8*)(kgh + (size_t)(k0 + krow) * CC + koff);
        f16x8 rkl = *(const f16x8*)(kgl + (size_t)(k0 + krow) * CC + koff);
        f16x8 rvh = *(const f16x8*)(vgh + k0 + voff);
        __syncthreads();  // previous tile fully consumed
        *(f16x8*)dKh = rkh;
        *(f16x8*)dKl = rkl;
        *(f16x8*)dVh = rvh;
        __syncthreads();

        // ---- QK^T (S^T = K·Q^T): 4 key subtiles, split precision ----
        f32x4 s[4];
#pragma unroll
        for (int kt = 0; kt < 4; ++kt) {
            f16x8 ka = *(const f16x8*)(fKh + kt * 16 * 40);
            f16x8 kb = *(const f16x8*)(fKl + kt * 16 * 40);
            f32x4 z = {0.f, 0.f, 0.f, 0.f};
            z = __builtin_amdgcn_mfma_f32_16x16x32_f16(ka, qh, z, 0, 0, 0);
            z = __builtin_amdgcn_mfma_f32_16x16x32_f16(ka, ql, z, 0, 0, 0);
            z = __builtin_amdgcn_mfma_f32_16x16x32_f16(kb, qh, z, 0, 0, 0);
            s[kt] = z;
        }

        // ---- online softmax over 64 keys ----
        float tm = -1e30f;
#pragma unroll
        for (int kt = 0; kt < 4; ++kt)
#pragma unroll
            for (int r = 0; r < 4; ++r) tm = fmaxf(tm, s[kt][r]);
        tm = fmaxf(tm, __shfl_xor(tm, 16));
        tm = fmaxf(tm, __shfl_xor(tm, 32));
        float nm = fmaxf(mrun, tm);
        float alpha = __builtin_amdgcn_exp2f(mrun - nm);
        float p[16], rs = 0.f;
#pragma unroll
        for (int kt = 0; kt < 4; ++kt)
#pragma unroll
            for (int r = 0; r < 4; ++r) {
                float pv = __builtin_amdgcn_exp2f(s[kt][r] - nm);
                p[kt * 4 + r] = pv;
                rs += pv;
            }
        rs += __shfl_xor(rs, 16);
        rs += __shfl_xor(rs, 32);
        lsum = lsum * alpha + rs;
        mrun = nm;
        o0.x *= alpha; o0.y *= alpha; o0.z *= alpha; o0.w *= alpha;
        o1.x *= alpha; o1.y *= alpha; o1.z *= alpha; o1.w *= alpha;

        // ---- P (hi only) + per-wave LDS transpose ([q][key 0..63]) ----
#pragma unroll
        for (int kt = 0; kt < 4; ++kt) {
            f16x4 h4;
#pragma unroll
            for (int r = 0; r < 4; ++r) h4[r] = (_Float16)p[kt * 4 + r];
            *(f16x4*)(wPh + kt * 16) = h4;
        }
        __asm__ volatile("s_waitcnt lgkmcnt(0)" ::: "memory");
        f16x8 pH[2];
#pragma unroll
        for (int c = 0; c < 2; ++c) pH[c] = *(const f16x8*)(rPh + c * 32);

        // ---- PV: O^T += V^T · P^T (hi-only, 2 key chunks × 2 d-halves) ----
#pragma unroll
        for (int c = 0; c < 2; ++c) {
            f16x8 va = *(const f16x8*)(fVh0 + c * 32);
            o0 = __builtin_amdgcn_mfma_f32_16x16x32_f16(va, pH[c], o0, 0, 0, 0);
            f16x8 vc = *(const f16x8*)(fVh1 + c * 32);
            o1 = __builtin_amdgcn_mfma_f32_16x16x32_f16(vc, pH[c], o1, 0, 0, 0);
        }
    }

    // epilogue: O^T layout col=q, row=d. Write split O into Q buffer (own tokens).
    float inv = 1.f / lsum;
    f32x4 oo[2] = {o0, o1};
#pragma unroll
    for (int dh = 0; dh < 2; ++dh) {
        f16x4 h4, l4;
#pragma unroll
        for (int r = 0; r < 4; ++r) {
            hl16 s = split2(oo[dh][r] * inv);
            h4[r] = s.h;
            l4[r] = s.l;
        }
        size_t dsti = ((size_t)(b * NN + qbase + col)) * CC + h * DH + dh * 16 + quad * 4;
        *(f16x4*)&QOh[dsti] = h4;
        *(f16x4*)&QOl[dsti] = l4;
    }
}

// ---------------------------------------------------------------------------
__global__ __launch_bounds__(256) void add_ln_k(float* __restrict__ X,
                                                const float* __restrict__ P,
                                                const float* __restrict__ g,
                                                const float* __restrict__ bta,
                                                _Float16* __restrict__ Xh,
                                                _Float16* __restrict__ Xl) {
    int wave = threadIdx.x >> 6, lane = threadIdx.x & 63;
    size_t row = (size_t)blockIdx.x * 4 + wave;
    size_t base = row * CC + lane * 4;
    float4 x = *(float4*)(X + base);
    float4 p = *(const float4*)(P + base);
    x.x += p.x; x.y += p.y; x.z += p.z; x.w += p.w;
    float sum = x.x + x.y + x.z + x.w;
    float ss = x.x * x.x + x.y * x.y + x.z * x.z + x.w * x.w;
#pragma unroll
    for (int off = 32; off; off >>= 1) {
        sum += __shfl_down(sum, off);
        ss += __shfl_down(ss, off);
    }
    sum = __shfl(sum, 0);
    ss = __shfl(ss, 0);
    float mean = sum * (1.f / 256.f);
    float var = ss * (1.f / 256.f) - mean * mean;
    float wn = rsqrtf(var + EPSV);
    float4 gg = *(const float4*)(g + lane * 4);
    float4 bb = *(const float4*)(bta + lane * 4);
    x.x = (x.x - mean) * wn * gg.x + bb.x;
    x.y = (x.y - mean) * wn * gg.y + bb.y;
    x.z = (x.z - mean) * wn * gg.z + bb.z;
    x.w = (x.w - mean) * wn * gg.w + bb.w;
    *(float4*)(X + base) = x;
    f16x4 h4, l4;
    float xv[4] = {x.x, x.y, x.z, x.w};
#pragma unroll
    for (int j = 0; j < 4; ++j) {
        hl16 s = split2(xv[j]);
        h4[j] = s.h;
        l4[j] = s.l;
    }
    *(f16x4*)&Xh[base] = h4;
    *(f16x4*)&Xl[base] = l4;
}

// ---------------------------------------------------------------------------
// Conv-path BN apply (from raw sums) + LeakyReLU + split to fp16 hi/lo.
__global__ __launch_bounds__(256) void applyc_k(const float* __restrict__ in,
                                                _Float16* __restrict__ oh,
                                                _Float16* __restrict__ ol,
                                                const float* __restrict__ st,
                                                const float* __restrict__ gam,
                                                const float* __restrict__ bet,
                                                int total, int Cc, float invM) {
    int i = blockIdx.x * 256 + threadIdx.x;
    if (i >= total) return;
    int c = i % Cc;
    float mean = st[c] * invM;
    float var = st[Cc + c] * invM - mean * mean;
    float sc = rsqrtf(var + EPSV) * gam[c];
    float v = fmaf(in[i] - mean, sc, bet[c]);
    v = v > 0.f ? v : 0.2f * v;
    hl16 s = split2(v);
    oh[i] = s.h;
    ol[i] = s.l;
}

// ---------------------------------------------------------------------------
// Fused: BN3(raw sums)+ReLU -> argmax -> ball query -> gather grouped coords.
__global__ __launch_bounds__(64) void select_k(const float* __restrict__ H3,
                                               const float* __restrict__ pts,
                                               const float* __restrict__ st,
                                               const float* __restrict__ gam,
                                               const float* __restrict__ bet,
                                               float* __restrict__ G0) {
    int bs = blockIdx.x;
    int b = bs >> 4, ch = bs & 15;
    int lane = threadIdx.x;
    float mean = st[ch] * INV_MF;
    float var = st[16 + ch] * INV_MF - mean * mean;
    float sc = rsqrtf(var + EPSV) * gam[ch];
    float sh = bet[ch] - mean * sc;
    float best = -1e30f;
    int bn = 0;
    for (int n = lane; n < NN; n += 64) {
        float v = fmaf(H3[((size_t)(b * NN + n)) * 16 + ch], sc, sh);
        v = fmaxf(v, 0.f);
        if (v > best) { best = v; bn = n; }
    }
#pragma unroll
    for (int off = 32; off; off >>= 1) {
        float ov = __shfl_xor(best, off);
        int on = __shfl_xor(bn, off);
        if (ov > best || (ov == best && on < bn)) { best = ov; bn = on; }
    }
    const float* px = pts + (size_t)b * 3 * NN;
    float qx = px[bn], qy = px[NN + bn], qz = px[2 * NN + bn];
    float qq = (qx * qx + qy * qy) + qz * qz;
    __shared__ int sgi[NSAMPLE];
    const float R2 = 0.09f;
    int cnt = 0;
    for (int base = 0; base < NN && cnt < NSAMPLE; base += 64) {
        int n = base + lane;
        float x = px[n], y = px[NN + n], z = px[2 * NN + n];
        float pp = (x * x + y * y) + z * z;
        float dot = (qx * x + qy * y) + qz * z;
        float sqd = (qq + pp) - 2.f * dot;
        bool ok = !(sqd > R2);
        unsigned long long mk = __ballot(ok);
        int pos = cnt + (int)__popcll(mk & ((1ull << lane) - 1ull));
        if (ok && pos < NSAMPLE) sgi[pos] = n;
        cnt += (int)__popcll(mk);
    }
    __syncthreads();
    int g0 = sgi[0];
    if (lane >= cnt && lane < NSAMPLE) sgi[lane] = g0;
    __syncthreads();
    for (int e = lane; e < KK * 3; e += 64) {
        int k = e / 3, d = e % 3;
        int src = (k == 0) ? bn : sgi[k - 1];
        G0[((size_t)bs * KK + k) * 3 + d] = px[d * NN + src];
    }
}

// ---------------------------------------------------------------------------
// Fused BN(C3, raw sums)+LeakyReLU+max over k.
__global__ __launch_bounds__(256) void maxpool_k(const float* __restrict__ G3,
                                                 const float* __restrict__ st,
                                                 const float* __restrict__ gam,
                                                 const float* __restrict__ bet,
                                                 float* __restrict__ out) {
    int i = blockIdx.x * 256 + threadIdx.x;
    if (i >= BB * 512 * SS) return;
    int o = i & 511;
    int s = (i >> 9) & 15;
    int b = i >> 13;
    float mean = st[o] * INV_MG;
    float var = st[512 + o] * INV_MG - mean * mean;
    float sc = rsqrtf(var + EPSV) * gam[o];
    float sh = bet[o] - mean * sc;
    const float* p = G3 + ((size_t)(b * SS + s) * KK) * 512 + o;
    float mx = -1e30f;
#pragma unroll
    for (int k = 0; k < KK; ++k) {
        float v = fmaf(p[(size_t)k * 512], sc, sh);
        v = v > 0.f ? v : 0.2f * v;
        mx = fmaxf(mx, v);
    }
    out[((size_t)(b * 512 + o)) * SS + s] = mx;
}

// ---------------------------------------------------------------------------
extern "C" void kernel_launch(void* const* d_in, const int* in_sizes, int n_in,
                              void* d_out, int out_size, void* d_ws, size_t ws_size,
                              hipStream_t stream) {
    const float* hoch = (const float*)d_in[0];
    const float* pts = (const float*)d_in[1];
    const float* Wq = (const float*)d_in[2];
    const float* Wk = (const float*)d_in[3];
    const float* Wv = (const float*)d_in[4];
    const float* Wo = (const float*)d_in[5];
    const float* ln_g = (const float*)d_in[6];
    const float* ln_b = (const float*)d_in[7];
    const float* fg_w1 = (const float*)d_in[8];
    const float* fg_b1 = (const float*)d_in[9];
    const float* fg_w2 = (const float*)d_in[10];
    const float* fg_b2 = (const float*)d_in[11];
    const float* fg_w3 = (const float*)d_in[12];
    const float* fg_b3 = (const float*)d_in[13];
    const float* fg_g1 = (const float*)d_in[14];
    const float* fg_be1 = (const float*)d_in[15];
    const float* fg_g2 = (const float*)d_in[16];
    const float* fg_be2 = (const float*)d_in[17];
    const float* fg_g3 = (const float*)d_in[18];
    const float* fg_be3 = (const float*)d_in[19];
    const float* cw1 = (const float*)d_in[20];
    const float* cw2 = (const float*)d_in[21];
    const float* cw3 = (const float*)d_in[22];
    const float* cg1 = (const float*)d_in[23];
    const float* cb1 = (const float*)d_in[24];
    const float* cg2 = (const float*)d_in[25];
    const float* cb2 = (const float*)d_in[26];
    const float* cg3 = (const float*)d_in[27];
    const float* cb3 = (const float*)d_in[28];
    float* out = (float*)d_out;

    float* ws = (float*)d_ws;
    const size_t M1 = (size_t)BB * NN * CC;  // 2,097,152
    float* X = ws;
    float* bA = ws + M1;
    float* bB = ws + 2 * M1;
    float* bC = ws + 3 * M1;
    _Float16* hb = (_Float16*)(ws + 4 * M1);
    _Float16* Xh = hb;
    _Float16* Xl = hb + M1;
    _Float16* Qh = hb + 2 * M1;  // also O (attn writes split O back here)
    _Float16* Ql = hb + 3 * M1;
    _Float16* Kh = hb + 4 * M1;  // also conv activations post-transformer
    _Float16* Kl = hb + 5 * M1;
    _Float16* Vh = hb + 6 * M1;
    _Float16* Vl = hb + 7 * M1;
    _Float16* wt = hb + 8 * M1;  // 1,376,256 halves
    float* sm = ws + 4 * M1 + (9 * M1) / 2;
    float* st1 = sm;
    float* st2 = sm + 1024;
    float* st3 = sm + 2048;
    float* st4 = sm + 3072;
    float* st5 = sm + 4096;
    float* st6 = sm + 5120;
    float* G0 = sm + 8192;  // 6336

    prep_split_k<<<2688, 256, 0, stream>>>(Wq, Wk, Wv, Wo, fg_w1, cw2, cw3, wt, sm);
    transpose_split_k<<<dim3(NN / 32, CC / 32, BB), dim3(32, 8), 0, stream>>>(hoch, X, Xh, Xl);

    const int Mrows = BB * NN;  // 8192
    for (int l = 0; l < LL; ++l) {
        qkv_h_k<<<dim3(12, Mrows / 128), 256, 0, stream>>>(Xh, Xl, wt, l, Qh, Ql, Kh, Kl, Vh, Vl);
        attn7_k<<<dim3(NN / 64, BB * HH), 256, 0, stream>>>(Qh, Ql, Kh, Kl, Vh, Vl);
        int slot = (l * 4 + 3) * 2;
        gemm_h_k<128><<<dim3(CC / 64, Mrows / 128), 256, 0, stream>>>(
            Qh, Ql, wt + (size_t)slot * WT_SLOT, wt + (size_t)(slot + 1) * WT_SLOT,
            nullptr, bA, CC, CC, nullptr);
        add_ln_k<<<Mrows / 4, 256, 0, stream>>>(X, bA, ln_g + l * CC, ln_b + l * CC, Xh, Xl);
    }

    // fg head: 256 -> 64 -> 32 -> 16; stats fused in epilogues, BN fused forward
    gemm_h_k<64><<<dim3(1, Mrows / 64), 256, 0, stream>>>(Xh, Xl, wt + FG1H_OFF, wt + FG1L_OFF, fg_b1, bA, 64, 256, st1);
    gemm_k<true, true><<<dim3(1, Mrows / 64), 256, 0, stream>>>(bA, fg_w2, fg_b2, bB, Mrows, 32, 64,
                                                                st1, fg_g1, fg_be1, INV_MF, st2);
    gemm_k<true, true><<<dim3(1, Mrows / 64), 256, 0, stream>>>(bB, fg_w3, fg_b3, bC, Mrows, 16, 32,
                                                                st2, fg_g2, fg_be2, INV_MF, st3);

    // selection + grouping (applies BN3+ReLU internally)
    select_k<<<BB * SS, 64, 0, stream>>>(bC, pts, st3, fg_g3, fg_be3, G0);

    // conv stack: 3 -> 64 -> 256 -> 512
    const int Mg = BB * SS * KK;  // 2112 = 33*64
    gemm_k<true, false><<<dim3(1, Mg / 64), 256, 0, stream>>>(G0, cw1, nullptr, bA, Mg, 64, 3,
                                                              nullptr, nullptr, nullptr, 0.f, st4);
    applyc_k<<<(Mg * 64 + 255) / 256, 256, 0, stream>>>(bA, Kh, Kl, st4, cg1, cb1, Mg * 64, 64, INV_MG);
    gemm_h_k<64><<<dim3(4, Mg / 64), 256, 0, stream>>>(Kh, Kl, wt + CW2H_OFF, wt + CW2L_OFF, nullptr, bB, 256, 64, st5);
    applyc_k<<<(Mg * 256 + 255) / 256, 256, 0, stream>>>(bB, Kh, Kl, st5, cg2, cb2, Mg * 256, 256, INV_MG);
    gemm_h_k<64><<<dim3(8, Mg / 64), 256, 0, stream>>>(Kh, Kl, wt + CW3H_OFF, wt + CW3L_OFF, nullptr, bC, 512, 256, st6);

    // fused BN(C3)+LeakyReLU+maxpool
    maxpool_k<<<(BB * 512 * SS + 255) / 256, 256, 0, stream>>>(bC, st6, cg3, cb3, out);

    (void)in_sizes; (void)n_in; (void)out_size; (void)ws_size;
}

// Round 14
// 409.472 us; speedup vs baseline: 1.1990x; 1.0103x over previous
//
#include <hip/hip_runtime.h>
#include <hip/hip_bf16.h>
#include <math.h>

// Problem constants
#define BB 4
#define NN 2048
#define CC 256
#define HH 8
#define DH 32
#define LL 2
#define SS 16
#define KK 33
#define NSAMPLE 32
#define EPSV 1e-5f

typedef _Float16 f16x8 __attribute__((ext_vector_type(8)));
typedef _Float16 f16x4 __attribute__((ext_vector_type(4)));
typedef float f32x4 __attribute__((ext_vector_type(4)));

struct hl16 { _Float16 h, l; };
__device__ __forceinline__ hl16 split2(float v) {
    hl16 r;
    r.h = (_Float16)v;
    r.l = (_Float16)(v - (float)r.h);
    return r;
}

#define INV_MF (1.f / 8192.f)
#define INV_MG (1.f / 2112.f)

// Pre-split weight table offsets (in halves)
#define WT_SLOT 65536
#define FG1H_OFF 1048576
#define FG1L_OFF (FG1H_OFF + 16384)
#define CW2H_OFF (FG1H_OFF + 32768)
#define CW2L_OFF (FG1H_OFF + 49152)
#define CW3H_OFF (FG1H_OFF + 65536)
#define CW3L_OFF (CW3H_OFF + 131072)

// ---------------------------------------------------------------------------
// One-time: zero stats regions + split all MFMA-path weights to fp16 hi/lo.
__global__ __launch_bounds__(256) void prep_split_k(
    const float* __restrict__ Wq, const float* __restrict__ Wk,
    const float* __restrict__ Wv, const float* __restrict__ Wo,
    const float* __restrict__ fgw1, const float* __restrict__ cw2,
    const float* __restrict__ cw3, _Float16* __restrict__ wt,
    float* __restrict__ stats0) {
    int e = blockIdx.x * 256 + threadIdx.x;
    if (e < 6144) stats0[e] = 0.f;
    if (e < 524288) {
        int slot = e >> 16;  // l*4 + mat
        int l = slot >> 2, mat = slot & 3;
        int r = e & 65535;
        int n = r >> 8, k = r & 255;
        const float* W = mat == 0 ? Wq : mat == 1 ? Wk : mat == 2 ? Wv : Wo;
        hl16 s = split2(W[(size_t)l * 65536 + k * 256 + n]);
        wt[(size_t)(2 * slot) * WT_SLOT + n * 256 + k] = s.h;
        wt[(size_t)(2 * slot + 1) * WT_SLOT + n * 256 + k] = s.l;
    } else if (e < 524288 + 16384) {
        int r = e - 524288;
        hl16 s = split2(fgw1[r]);
        wt[FG1H_OFF + r] = s.h;
        wt[FG1L_OFF + r] = s.l;
    } else if (e < 524288 + 32768) {
        int r = e - (524288 + 16384);
        hl16 s = split2(cw2[r]);
        wt[CW2H_OFF + r] = s.h;
        wt[CW2L_OFF + r] = s.l;
    } else if (e < 524288 + 32768 + 131072) {
        int r = e - (524288 + 32768);
        hl16 s = split2(cw3[r]);
        wt[CW3H_OFF + r] = s.h;
        wt[CW3L_OFF + r] = s.l;
    }
}

// ---------------------------------------------------------------------------
__global__ __launch_bounds__(256) void transpose_split_k(const float* __restrict__ in,
                                                         float* __restrict__ out,
                                                         _Float16* __restrict__ oh,
                                                         _Float16* __restrict__ ol) {
    __shared__ float tls[32][33];
    int n0 = blockIdx.x * 32, c0 = blockIdx.y * 32, b = blockIdx.z;
    const float* ip = in + (size_t)b * CC * NN;
    size_t ob = (size_t)b * NN * CC;
    int tx = threadIdx.x, ty = threadIdx.y;
#pragma unroll
    for (int i = 0; i < 4; ++i)
        tls[ty + i * 8][tx] = ip[(size_t)(c0 + ty + i * 8) * NN + n0 + tx];
    __syncthreads();
#pragma unroll
    for (int i = 0; i < 4; ++i) {
        size_t oi = ob + (size_t)(n0 + ty + i * 8) * CC + c0 + tx;
        float v = tls[tx][ty + i * 8];
        out[oi] = v;
        hl16 s = split2(v);
        oh[oi] = s.h;
        ol[oi] = s.l;
    }
}

// ---------------------------------------------------------------------------
// fp32 GEMM with optional fused input-BN+ReLU (staging) and output-stats.
template <bool TRANSB, bool BIAS>
__global__ __launch_bounds__(256) void gemm_k(const float* __restrict__ A,
                                              const float* __restrict__ Bm,
                                              const float* __restrict__ bias,
                                              float* __restrict__ Cm,
                                              int M, int Nc, int K,
                                              const float* __restrict__ pst,
                                              const float* __restrict__ pg,
                                              const float* __restrict__ pb,
                                              float pInvM,
                                              float* __restrict__ ost) {
    __shared__ float As[16][68];
    __shared__ float Bs[16][68];
    __shared__ float sSc[64], sSh[64];
    int t = threadIdx.x;
    int tx = t & 15, ty = t >> 4;
    int row0 = blockIdx.y * 64, col0 = blockIdx.x * 64;
    if (pst && t < K) {
        float mean = pst[t] * pInvM;
        float var = pst[K + t] * pInvM - mean * mean;
        float wv = rsqrtf(var + EPSV) * pg[t];
        sSc[t] = wv;
        sSh[t] = pb[t] - mean * wv;
    }
    if (pst) __syncthreads();
    float acc[4][4] = {};
    for (int k0 = 0; k0 < K; k0 += 16) {
#pragma unroll
        for (int p = 0; p < 4; ++p) {
            int i = t + 256 * p;
            int m = i >> 4, k = i & 15;
            int gm = row0 + m, gk = k0 + k;
            float av = 0.f;
            if (gm < M && gk < K) {
                av = A[(size_t)gm * K + gk];
                if (pst) {
                    av = fmaf(av, sSc[gk], sSh[gk]);
                    av = fmaxf(av, 0.f);
                }
            }
            As[k][m] = av;
        }
#pragma unroll
        for (int p = 0; p < 4; ++p) {
            int i = t + 256 * p;
            if (TRANSB) {
                int k = i & 15, n = i >> 4;
                int gn = col0 + n, gk = k0 + k;
                Bs[k][n] = (gn < Nc && gk < K) ? Bm[(size_t)gn * K + gk] : 0.f;
            } else {
                int n = i & 63, k = i >> 6;
                int gn = col0 + n, gk = k0 + k;
                Bs[k][n] = (gn < Nc && gk < K) ? Bm[(size_t)gk * Nc + gn] : 0.f;
            }
        }
        __syncthreads();
#pragma unroll
        for (int kk = 0; kk < 16; ++kk) {
            float4 a4 = *(const float4*)&As[kk][ty * 4];
            float4 b4 = *(const float4*)&Bs[kk][tx * 4];
            float av[4] = {a4.x, a4.y, a4.z, a4.w};
            float bv[4] = {b4.x, b4.y, b4.z, b4.w};
#pragma unroll
            for (int i = 0; i < 4; ++i)
#pragma unroll
                for (int j = 0; j < 4; ++j) acc[i][j] = fmaf(av[i], bv[j], acc[i][j]);
        }
        __syncthreads();
    }
    float cs[4] = {}, css[4] = {};
#pragma unroll
    for (int i = 0; i < 4; ++i) {
        int r = row0 + ty * 4 + i;
        if (r >= M) continue;
#pragma unroll
        for (int j = 0; j < 4; ++j) {
            int c = col0 + tx * 4 + j;
            if (c >= Nc) continue;
            float v = acc[i][j];
            if (BIAS) v += bias[c];
            Cm[(size_t)r * Nc + c] = v;
            cs[j] += v;
            css[j] += v * v;
        }
    }
    if (ost) {
        float* sc = &As[0][0];  // 128 floats scratch
        if (t < 128) sc[t] = 0.f;
        __syncthreads();
#pragma unroll
        for (int j = 0; j < 4; ++j) {
            atomicAdd(&sc[tx * 4 + j], cs[j]);
            atomicAdd(&sc[64 + tx * 4 + j], css[j]);
        }
        __syncthreads();
        if (t < Nc) atomicAdd(&ost[t], sc[t]);
        else if (t >= 64 && t - 64 < Nc) atomicAdd(&ost[Nc + t - 64], sc[t]);
    }
}

// ---------------------------------------------------------------------------
// Pre-split fp16 MFMA GEMM. A: Ah/Al [M][K] fp16; B: Bh/Bl [N][K] fp16.
#define EPI_F32 0
#define EPI_QK 1
#define EPI_VT 2

template <int TM>
__device__ __forceinline__ void gemm_h_body(
    const _Float16* __restrict__ Ah, const _Float16* __restrict__ Al,
    const _Float16* __restrict__ Bh, const _Float16* __restrict__ Bl,
    const float* __restrict__ bias, float* __restrict__ Cf,
    _Float16* __restrict__ Ch, _Float16* __restrict__ Cl,
    int Nc, int K, int row0, int col0, int mode, float scl,
    float* __restrict__ ost,
    _Float16* sAh, _Float16* sAl, _Float16* sBh, _Float16* sBl) {
    int t = threadIdx.x, w = t >> 6, lane = t & 63;
    int col = lane & 15, quad = lane >> 4;
    const int m0w = (TM == 128) ? (w & 1) * 64 : 0;
    const int n0w = (TM == 128) ? (w >> 1) * 32 : w * 16;
    constexpr int NT = (TM == 128) ? 2 : 1;
    constexpr int AC = TM / 64;
    f32x4 acc[4][NT];
#pragma unroll
    for (int i = 0; i < 4; ++i)
#pragma unroll
        for (int j = 0; j < NT; ++j) acc[i][j] = (f32x4){0.f, 0.f, 0.f, 0.f};

    for (int k0 = 0; k0 < K; k0 += 32) {
        f16x8 rah[AC], ral[AC], rbh, rbl;
#pragma unroll
        for (int i = 0; i < AC; ++i) {
            int idx = t + 256 * i;
            int r = idx >> 2, off = (idx & 3) * 8;
            rah[i] = *(const f16x8*)(Ah + (size_t)(row0 + r) * K + k0 + off);
            ral[i] = *(const f16x8*)(Al + (size_t)(row0 + r) * K + k0 + off);
        }
        {
            int r = t >> 2, off = (t & 3) * 8;
            rbh = *(const f16x8*)(Bh + (size_t)(col0 + r) * K + k0 + off);
            rbl = *(const f16x8*)(Bl + (size_t)(col0 + r) * K + k0 + off);
        }
        __syncthreads();
#pragma unroll
        for (int i = 0; i < AC; ++i) {
            int idx = t + 256 * i;
            int r = idx >> 2, off = (idx & 3) * 8;
            *(f16x8*)&sAh[r * 40 + off] = rah[i];
            *(f16x8*)&sAl[r * 40 + off] = ral[i];
        }
        {
            int r = t >> 2, off = (t & 3) * 8;
            *(f16x8*)&sBh[r * 40 + off] = rbh;
            *(f16x8*)&sBl[r * 40 + off] = rbl;
        }
        __syncthreads();
        f16x8 fah[4], fal[4], fbh[NT], fbl[NT];
#pragma unroll
        for (int i = 0; i < 4; ++i) {
            fah[i] = *(const f16x8*)&sAh[(m0w + i * 16 + col) * 40 + quad * 8];
            fal[i] = *(const f16x8*)&sAl[(m0w + i * 16 + col) * 40 + quad * 8];
        }
#pragma unroll
        for (int j = 0; j < NT; ++j) {
            fbh[j] = *(const f16x8*)&sBh[(n0w + j * 16 + col) * 40 + quad * 8];
            fbl[j] = *(const f16x8*)&sBl[(n0w + j * 16 + col) * 40 + quad * 8];
        }
#pragma unroll
        for (int i = 0; i < 4; ++i)
#pragma unroll
            for (int j = 0; j < NT; ++j) {
                acc[i][j] = __builtin_amdgcn_mfma_f32_16x16x32_f16(fah[i], fbh[j], acc[i][j], 0, 0, 0);
                acc[i][j] = __builtin_amdgcn_mfma_f32_16x16x32_f16(fah[i], fbl[j], acc[i][j], 0, 0, 0);
                acc[i][j] = __builtin_amdgcn_mfma_f32_16x16x32_f16(fal[i], fbh[j], acc[i][j], 0, 0, 0);
            }
    }
    float s = 0.f, ss = 0.f;
#pragma unroll
    for (int i = 0; i < 4; ++i)
#pragma unroll
        for (int j = 0; j < NT; ++j) {
            int n = col0 + n0w + j * 16 + col;
            int mb = row0 + m0w + i * 16 + quad * 4;
            if (mode == EPI_F32) {
                float bv = bias ? bias[n] : 0.f;
#pragma unroll
                for (int r = 0; r < 4; ++r) {
                    float v = acc[i][j][r] + bv;
                    Cf[(size_t)(mb + r) * Nc + n] = v;
                    s += v;
                    ss += v * v;
                }
            } else if (mode == EPI_QK) {
#pragma unroll
                for (int r = 0; r < 4; ++r) {
                    hl16 sp = split2(acc[i][j][r] * scl);
                    Ch[(size_t)(mb + r) * Nc + n] = sp.h;
                    Cl[(size_t)(mb + r) * Nc + n] = sp.l;
                }
            } else {  // EPI_VT: [b][h][d][token]
                int b = mb >> 11, token = mb & 2047;
                int h = n >> 5, d = n & 31;
                f16x4 h4, l4;
#pragma unroll
                for (int r = 0; r < 4; ++r) {
                    hl16 sp = split2(acc[i][j][r]);
                    h4[r] = sp.h;
                    l4[r] = sp.l;
                }
                size_t dst = ((size_t)(b * HH + h) * DH + d) * NN + token;
                *(f16x4*)&Ch[dst] = h4;
                *(f16x4*)&Cl[dst] = l4;
            }
        }
    if (ost && mode == EPI_F32 && TM == 64) {
        s += __shfl_xor(s, 16);
        s += __shfl_xor(s, 32);
        ss += __shfl_xor(ss, 16);
        ss += __shfl_xor(ss, 32);
        if (quad == 0) {
            int n = col0 + n0w + col;
            atomicAdd(&ost[n], s);
            atomicAdd(&ost[Nc + n], ss);
        }
    }
}

template <int TM>
__global__ __launch_bounds__(256) void gemm_h_k(const _Float16* __restrict__ Ah,
                                                const _Float16* __restrict__ Al,
                                                const _Float16* __restrict__ Bh,
                                                const _Float16* __restrict__ Bl,
                                                const float* __restrict__ bias,
                                                float* __restrict__ Cf, int Nc, int K,
                                                float* __restrict__ ost) {
    __shared__ _Float16 sAh[TM * 40], sAl[TM * 40], sBh[64 * 40], sBl[64 * 40];
    gemm_h_body<TM>(Ah, Al, Bh, Bl, bias, Cf, nullptr, nullptr, Nc, K,
                    blockIdx.y * TM, blockIdx.x * 64, EPI_F32, 1.f, ost,
                    sAh, sAl, sBh, sBl);
}

// Fused QKV: blockIdx.x in [0,12): mat = x>>2, col block = x&3.
// Q scale folds 1/sqrt(dh) AND log2(e) (softmax uses exp2).
__global__ __launch_bounds__(256) void qkv_h_k(const _Float16* __restrict__ Xh,
                                               const _Float16* __restrict__ Xl,
                                               const _Float16* __restrict__ wt, int layer,
                                               _Float16* Qh, _Float16* Ql,
                                               _Float16* Kh, _Float16* Kl,
                                               _Float16* Vh, _Float16* Vl) {
    __shared__ _Float16 sAh[128 * 40], sAl[128 * 40], sBh[64 * 40], sBl[64 * 40];
    int mat = blockIdx.x >> 2;
    int slot = (layer * 4 + mat) * 2;
    const _Float16* Bh = wt + (size_t)slot * WT_SLOT;
    const _Float16* Bl = wt + (size_t)(slot + 1) * WT_SLOT;
    _Float16* Ch = mat == 0 ? Qh : mat == 1 ? Kh : Vh;
    _Float16* Cl = mat == 0 ? Ql : mat == 1 ? Kl : Vl;
    int mode = (mat == 2) ? EPI_VT : EPI_QK;
    float scl = (mat == 0) ? 0.25501654859214384f : 1.f;  // 1/sqrt(32)*log2(e)
    gemm_h_body<128>(Xh, Xl, Bh, Bl, nullptr, nullptr, Ch, Cl, CC, CC,
                     blockIdx.y * 128, (blockIdx.x & 3) * 64, mode, scl, nullptr,
                     sAh, sAl, sBh, sBl);
}

// ---------------------------------------------------------------------------
// MFMA GEMM, A fp32 with fused input-BN+LeakyReLU(0.2) + hi/lo split in
// staging; B pre-split fp16. Output fp32 + stats. TM=64; M%64==0, K%32==0.
__global__ __launch_bounds__(256) void gemm_hbn_k(const float* __restrict__ A,
                                                  const _Float16* __restrict__ Bh,
                                                  const _Float16* __restrict__ Bl,
                                                  float* __restrict__ Cf, int Nc, int K,
                                                  const float* __restrict__ pst,
                                                  const float* __restrict__ pg,
                                                  const float* __restrict__ pb,
                                                  float* __restrict__ ost) {
    __shared__ _Float16 sAh[64 * 40], sAl[64 * 40], sBh[64 * 40], sBl[64 * 40];
    __shared__ float sSc[256], sSh[256];
    int t = threadIdx.x, w = t >> 6, lane = t & 63;
    int col = lane & 15, quad = lane >> 4;
    int n0w = w * 16;
    int row0 = blockIdx.y * 64, col0 = blockIdx.x * 64;
    if (t < K) {
        float mean = pst[t] * INV_MG;
        float var = pst[K + t] * INV_MG - mean * mean;
        float wv = rsqrtf(var + EPSV) * pg[t];
        sSc[t] = wv;
        sSh[t] = pb[t] - mean * wv;
    }
    __syncthreads();
    f32x4 acc[4];
#pragma unroll
    for (int i = 0; i < 4; ++i) acc[i] = (f32x4){0.f, 0.f, 0.f, 0.f};

    int r = t >> 2, off = (t & 3) * 8;
    for (int k0 = 0; k0 < K; k0 += 32) {
        const float* ap = A + (size_t)(row0 + r) * K + k0 + off;
        float4 a0 = *(const float4*)ap;
        float4 a1 = *(const float4*)(ap + 4);
        f16x8 rbh = *(const f16x8*)(Bh + (size_t)(col0 + r) * K + k0 + off);
        f16x8 rbl = *(const f16x8*)(Bl + (size_t)(col0 + r) * K + k0 + off);
        float avv[8] = {a0.x, a0.y, a0.z, a0.w, a1.x, a1.y, a1.z, a1.w};
        f16x8 h8, l8;
#pragma unroll
        for (int j = 0; j < 8; ++j) {
            int c = k0 + off + j;
            float v = fmaf(avv[j], sSc[c], sSh[c]);
            v = v > 0.f ? v : 0.2f * v;
            hl16 sp = split2(v);
            h8[j] = sp.h;
            l8[j] = sp.l;
        }
        __syncthreads();
        *(f16x8*)&sAh[r * 40 + off] = h8;
        *(f16x8*)&sAl[r * 40 + off] = l8;
        *(f16x8*)&sBh[r * 40 + off] = rbh;
        *(f16x8*)&sBl[r * 40 + off] = rbl;
        __syncthreads();
        f16x8 fah[4], fal[4], fbh, fbl;
#pragma unroll
        for (int i = 0; i < 4; ++i) {
            fah[i] = *(const f16x8*)&sAh[(i * 16 + col) * 40 + quad * 8];
            fal[i] = *(const f16x8*)&sAl[(i * 16 + col) * 40 + quad * 8];
        }
        fbh = *(const f16x8*)&sBh[(n0w + col) * 40 + quad * 8];
        fbl = *(const f16x8*)&sBl[(n0w + col) * 40 + quad * 8];
#pragma unroll
        for (int i = 0; i < 4; ++i) {
            acc[i] = __builtin_amdgcn_mfma_f32_16x16x32_f16(fah[i], fbh, acc[i], 0, 0, 0);
            acc[i] = __builtin_amdgcn_mfma_f32_16x16x32_f16(fah[i], fbl, acc[i], 0, 0, 0);
            acc[i] = __builtin_amdgcn_mfma_f32_16x16x32_f16(fal[i], fbh, acc[i], 0, 0, 0);
        }
    }
    float s = 0.f, ss = 0.f;
#pragma unroll
    for (int i = 0; i < 4; ++i) {
        int n = col0 + n0w + col;
        int mb = row0 + i * 16 + quad * 4;
#pragma unroll
        for (int rr = 0; rr < 4; ++rr) {
            float v = acc[i][rr];
            Cf[(size_t)(mb + rr) * Nc + n] = v;
            s += v;
            ss += v * v;
        }
    }
    s += __shfl_xor(s, 16);
    s += __shfl_xor(s, 32);
    ss += __shfl_xor(ss, 16);
    ss += __shfl_xor(ss, 32);
    if (quad == 0) {
        int n = col0 + n0w + col;
        atomicAdd(&ost[n], s);
        atomicAdd(&ost[Nc + n], ss);
    }
}

// ---------------------------------------------------------------------------
// Attention v7: 64-key tiles, split Q/K for scores, hi-only P·V.
__global__ __launch_bounds__(256) void attn7_k(_Float16* QOh, _Float16* QOl,
                                               const _Float16* __restrict__ Kh,
                                               const _Float16* __restrict__ Kl,
                                               const _Float16* __restrict__ Vh,
                                               const _Float16* __restrict__ Vl) {
    __shared__ _Float16 sKh[64 * 40], sKl[64 * 40];   // [key][d]
    __shared__ _Float16 sVh[32 * 72];                 // [d][key], hi only
    __shared__ _Float16 sPh[4][16 * 72];              // per-wave [q][key], hi only
    int t = threadIdx.x, w = t >> 6, lane = t & 63;
    int col = lane & 15, quad = lane >> 4;
    int bh = blockIdx.y, b = bh >> 3, h = bh & 7;
    int qbase = blockIdx.x * 64 + w * 16;

    size_t qoff = ((size_t)(b * NN + qbase + col)) * CC + h * DH + quad * 8;
    f16x8 qh = *(const f16x8*)(QOh + qoff);
    f16x8 ql = *(const f16x8*)(QOl + qoff);

    f32x4 o0 = {0.f, 0.f, 0.f, 0.f}, o1 = {0.f, 0.f, 0.f, 0.f};
    float mrun = -1e30f, lsum = 0.f;

    const _Float16* fKh = &sKh[col * 40 + quad * 8];
    const _Float16* fKl = &sKl[col * 40 + quad * 8];
    const _Float16* fVh0 = &sVh[col * 72 + quad * 8];
    const _Float16* fVh1 = &sVh[(16 + col) * 72 + quad * 8];
    _Float16* wPh = &sPh[w][col * 72 + quad * 4];
    const _Float16* rPh = &sPh[w][col * 72 + quad * 8];

    int krow = t >> 2, koff = (t & 3) * 8;   // K: [key][d], 64x32 halves
    int vrow = t >> 3, voff = (t & 7) * 8;   // V: [d][key], 32x64 halves
    const _Float16* kgh = Kh + (size_t)b * NN * CC + h * DH;
    const _Float16* kgl = Kl + (size_t)b * NN * CC + h * DH;
    const _Float16* vgh = Vh + ((size_t)(b * HH + h) * DH + vrow) * NN;
    _Float16* dKh = sKh + krow * 40 + koff;
    _Float16* dKl = sKl + krow * 40 + koff;
    _Float16* dVh = sVh + vrow * 72 + voff;
    (void)Vl;

    for (int k0 = 0; k0 < NN; k0 += 64) {
        f16x8 rkh = *(const f16x8*)(kgh + (size_t)(k0 + krow) * CC + koff);
        f16x8 rkl = *(const f16x8*)(kgl + (size_t)(k0 + krow) * CC + koff);
        f16x8 rvh = *(const f16x8*)(vgh + k0 + voff);
        __syncthreads();
        *(f16x8*)dKh = rkh;
        *(f16x8*)dKl = rkl;
        *(f16x8*)dVh = rvh;
        __syncthreads();

        f32x4 s[4];
#pragma unroll
        for (int kt = 0; kt < 4; ++kt) {
            f16x8 ka = *(const f16x8*)(fKh + kt * 16 * 40);
            f16x8 kb = *(const f16x8*)(fKl + kt * 16 * 40);
            f32x4 z = {0.f, 0.f, 0.f, 0.f};
            z = __builtin_amdgcn_mfma_f32_16x16x32_f16(ka, qh, z, 0, 0, 0);
            z = __builtin_amdgcn_mfma_f32_16x16x32_f16(ka, ql, z, 0, 0, 0);
            z = __builtin_amdgcn_mfma_f32_16x16x32_f16(kb, qh, z, 0, 0, 0);
            s[kt] = z;
        }

        float tm = -1e30f;
#pragma unroll
        for (int kt = 0; kt < 4; ++kt)
#pragma unroll
            for (int r = 0; r < 4; ++r) tm = fmaxf(tm, s[kt][r]);
        tm = fmaxf(tm, __shfl_xor(tm, 16));
        tm = fmaxf(tm, __shfl_xor(tm, 32));
        float nm = fmaxf(mrun, tm);
        float alpha = __builtin_amdgcn_exp2f(mrun - nm);
        float p[16], rs = 0.f;
#pragma unroll
        for (int kt = 0; kt < 4; ++kt)
#pragma unroll
            for (int r = 0; r < 4; ++r) {
                float pv = __builtin_amdgcn_exp2f(s[kt][r] - nm);
                p[kt * 4 + r] = pv;
                rs += pv;
            }
        rs += __shfl_xor(rs, 16);
        rs += __shfl_xor(rs, 32);
        lsum = lsum * alpha + rs;
        mrun = nm;
        o0.x *= alpha; o0.y *= alpha; o0.z *= alpha; o0.w *= alpha;
        o1.x *= alpha; o1.y *= alpha; o1.z *= alpha; o1.w *= alpha;

#pragma unroll
        for (int kt = 0; kt < 4; ++kt) {
            f16x4 h4;
#pragma unroll
            for (int r = 0; r < 4; ++r) h4[r] = (_Float16)p[kt * 4 + r];
            *(f16x4*)(wPh + kt * 16) = h4;
        }
        __asm__ volatile("s_waitcnt lgkmcnt(0)" ::: "memory");
        f16x8 pH[2];
#pragma unroll
        for (int c = 0; c < 2; ++c) pH[c] = *(const f16x8*)(rPh + c * 32);

#pragma unroll
        for (int c = 0; c < 2; ++c) {
            f16x8 va = *(const f16x8*)(fVh0 + c * 32);
            o0 = __builtin_amdgcn_mfma_f32_16x16x32_f16(va, pH[c], o0, 0, 0, 0);
            f16x8 vc = *(const f16x8*)(fVh1 + c * 32);
            o1 = __builtin_amdgcn_mfma_f32_16x16x32_f16(vc, pH[c], o1, 0, 0, 0);
        }
    }

    float inv = 1.f / lsum;
    f32x4 oo[2] = {o0, o1};
#pragma unroll
    for (int dh = 0; dh < 2; ++dh) {
        f16x4 h4, l4;
#pragma unroll
        for (int r = 0; r < 4; ++r) {
            hl16 s = split2(oo[dh][r] * inv);
            h4[r] = s.h;
            l4[r] = s.l;
        }
        size_t dsti = ((size_t)(b * NN + qbase + col)) * CC + h * DH + dh * 16 + quad * 4;
        *(f16x4*)&QOh[dsti] = h4;
        *(f16x4*)&QOl[dsti] = l4;
    }
}

// ---------------------------------------------------------------------------
__global__ __launch_bounds__(256) void add_ln_k(float* __restrict__ X,
                                                const float* __restrict__ P,
                                                const float* __restrict__ g,
                                                const float* __restrict__ bta,
                                                _Float16* __restrict__ Xh,
                                                _Float16* __restrict__ Xl) {
    int wave = threadIdx.x >> 6, lane = threadIdx.x & 63;
    size_t row = (size_t)blockIdx.x * 4 + wave;
    size_t base = row * CC + lane * 4;
    float4 x = *(float4*)(X + base);
    float4 p = *(const float4*)(P + base);
    x.x += p.x; x.y += p.y; x.z += p.z; x.w += p.w;
    float sum = x.x + x.y + x.z + x.w;
    float ss = x.x * x.x + x.y * x.y + x.z * x.z + x.w * x.w;
#pragma unroll
    for (int off = 32; off; off >>= 1) {
        sum += __shfl_down(sum, off);
        ss += __shfl_down(ss, off);
    }
    sum = __shfl(sum, 0);
    ss = __shfl(ss, 0);
    float mean = sum * (1.f / 256.f);
    float var = ss * (1.f / 256.f) - mean * mean;
    float wn = rsqrtf(var + EPSV);
    float4 gg = *(const float4*)(g + lane * 4);
    float4 bb = *(const float4*)(bta + lane * 4);
    x.x = (x.x - mean) * wn * gg.x + bb.x;
    x.y = (x.y - mean) * wn * gg.y + bb.y;
    x.z = (x.z - mean) * wn * gg.z + bb.z;
    x.w = (x.w - mean) * wn * gg.w + bb.w;
    *(float4*)(X + base) = x;
    f16x4 h4, l4;
    float xv[4] = {x.x, x.y, x.z, x.w};
#pragma unroll
    for (int j = 0; j < 4; ++j) {
        hl16 s = split2(xv[j]);
        h4[j] = s.h;
        l4[j] = s.l;
    }
    *(f16x4*)&Xh[base] = h4;
    *(f16x4*)&Xl[base] = l4;
}

// ---------------------------------------------------------------------------
// Fused: BN3(raw sums)+ReLU -> argmax -> ball query -> gather -> conv1(3->64)
// with output stats. One 64-lane block per (b, channel); lane = conv1 out chan.
__global__ __launch_bounds__(64) void select_k(const float* __restrict__ H3,
                                               const float* __restrict__ pts,
                                               const float* __restrict__ st,
                                               const float* __restrict__ gam,
                                               const float* __restrict__ bet,
                                               const float* __restrict__ cw1,
                                               float* __restrict__ C1,
                                               float* __restrict__ ost) {
    int bs = blockIdx.x;
    int b = bs >> 4, ch = bs & 15;
    int lane = threadIdx.x;
    float mean = st[ch] * INV_MF;
    float var = st[16 + ch] * INV_MF - mean * mean;
    float sc = rsqrtf(var + EPSV) * gam[ch];
    float sh = bet[ch] - mean * sc;
    float best = -1e30f;
    int bn = 0;
    for (int n = lane; n < NN; n += 64) {
        float v = fmaf(H3[((size_t)(b * NN + n)) * 16 + ch], sc, sh);
        v = fmaxf(v, 0.f);
        if (v > best) { best = v; bn = n; }
    }
#pragma unroll
    for (int off = 32; off; off >>= 1) {
        float ov = __shfl_xor(best, off);
        int on = __shfl_xor(bn, off);
        if (ov > best || (ov == best && on < bn)) { best = ov; bn = on; }
    }
    const float* px = pts + (size_t)b * 3 * NN;
    float qx = px[bn], qy = px[NN + bn], qz = px[2 * NN + bn];
    float qq = (qx * qx + qy * qy) + qz * qz;
    __shared__ int sgi[NSAMPLE];
    const float R2 = 0.09f;
    int cnt = 0;
    for (int base = 0; base < NN && cnt < NSAMPLE; base += 64) {
        int n = base + lane;
        float x = px[n], y = px[NN + n], z = px[2 * NN + n];
        float pp = (x * x + y * y) + z * z;
        float dot = (qx * x + qy * y) + qz * z;
        float sqd = (qq + pp) - 2.f * dot;
        bool ok = !(sqd > R2);
        unsigned long long mk = __ballot(ok);
        int pos = cnt + (int)__popcll(mk & ((1ull << lane) - 1ull));
        if (ok && pos < NSAMPLE) sgi[pos] = n;
        cnt += (int)__popcll(mk);
    }
    __syncthreads();
    int g0 = sgi[0];
    if (lane >= cnt && lane < NSAMPLE) sgi[lane] = g0;
    __syncthreads();
    // gather grouped coords into LDS
    __shared__ float sgc[KK][3];
    for (int e = lane; e < KK * 3; e += 64) {
        int k = e / 3, d = e % 3;
        int src = (k == 0) ? bn : sgi[k - 1];
        sgc[k][d] = px[d * NN + src];
    }
    __syncthreads();
    // conv1: lane = output channel (64); 33 points
    float w0 = cw1[lane * 3], w1 = cw1[lane * 3 + 1], w2 = cw1[lane * 3 + 2];
    float s = 0.f, ssum = 0.f;
#pragma unroll
    for (int k = 0; k < KK; ++k) {
        float v = w0 * sgc[k][0] + w1 * sgc[k][1] + w2 * sgc[k][2];
        C1[((size_t)bs * KK + k) * 64 + lane] = v;
        s += v;
        ssum += v * v;
    }
    atomicAdd(&ost[lane], s);
    atomicAdd(&ost[64 + lane], ssum);
}

// ---------------------------------------------------------------------------
// Fused BN(C3, raw sums)+LeakyReLU+max over k.
__global__ __launch_bounds__(256) void maxpool_k(const float* __restrict__ G3,
                                                 const float* __restrict__ st,
                                                 const float* __restrict__ gam,
                                                 const float* __restrict__ bet,
                                                 float* __restrict__ out) {
    int i = blockIdx.x * 256 + threadIdx.x;
    if (i >= BB * 512 * SS) return;
    int o = i & 511;
    int s = (i >> 9) & 15;
    int b = i >> 13;
    float mean = st[o] * INV_MG;
    float var = st[512 + o] * INV_MG - mean * mean;
    float sc = rsqrtf(var + EPSV) * gam[o];
    float sh = bet[o] - mean * sc;
    const float* p = G3 + ((size_t)(b * SS + s) * KK) * 512 + o;
    float mx = -1e30f;
#pragma unroll
    for (int k = 0; k < KK; ++k) {
        float v = fmaf(p[(size_t)k * 512], sc, sh);
        v = v > 0.f ? v : 0.2f * v;
        mx = fmaxf(mx, v);
    }
    out[((size_t)(b * 512 + o)) * SS + s] = mx;
}

// ---------------------------------------------------------------------------
extern "C" void kernel_launch(void* const* d_in, const int* in_sizes, int n_in,
                              void* d_out, int out_size, void* d_ws, size_t ws_size,
                              hipStream_t stream) {
    const float* hoch = (const float*)d_in[0];
    const float* pts = (const float*)d_in[1];
    const float* Wq = (const float*)d_in[2];
    const float* Wk = (const float*)d_in[3];
    const float* Wv = (const float*)d_in[4];
    const float* Wo = (const float*)d_in[5];
    const float* ln_g = (const float*)d_in[6];
    const float* ln_b = (const float*)d_in[7];
    const float* fg_w1 = (const float*)d_in[8];
    const float* fg_b1 = (const float*)d_in[9];
    const float* fg_w2 = (const float*)d_in[10];
    const float* fg_b2 = (const float*)d_in[11];
    const float* fg_w3 = (const float*)d_in[12];
    const float* fg_b3 = (const float*)d_in[13];
    const float* fg_g1 = (const float*)d_in[14];
    const float* fg_be1 = (const float*)d_in[15];
    const float* fg_g2 = (const float*)d_in[16];
    const float* fg_be2 = (const float*)d_in[17];
    const float* fg_g3 = (const float*)d_in[18];
    const float* fg_be3 = (const float*)d_in[19];
    const float* cw1 = (const float*)d_in[20];
    const float* cw2 = (const float*)d_in[21];
    const float* cw3 = (const float*)d_in[22];
    const float* cg1 = (const float*)d_in[23];
    const float* cb1 = (const float*)d_in[24];
    const float* cg2 = (const float*)d_in[25];
    const float* cb2 = (const float*)d_in[26];
    const float* cg3 = (const float*)d_in[27];
    const float* cb3 = (const float*)d_in[28];
    float* out = (float*)d_out;

    float* ws = (float*)d_ws;
    const size_t M1 = (size_t)BB * NN * CC;  // 2,097,152
    float* X = ws;
    float* bA = ws + M1;
    float* bB = ws + 2 * M1;
    float* bC = ws + 3 * M1;
    _Float16* hb = (_Float16*)(ws + 4 * M1);
    _Float16* Xh = hb;
    _Float16* Xl = hb + M1;
    _Float16* Qh = hb + 2 * M1;  // also O (attn writes split O back here)
    _Float16* Ql = hb + 3 * M1;
    _Float16* Kh = hb + 4 * M1;
    _Float16* Kl = hb + 5 * M1;
    _Float16* Vh = hb + 6 * M1;
    _Float16* Vl = hb + 7 * M1;
    _Float16* wt = hb + 8 * M1;  // 1,376,256 halves
    float* sm = ws + 4 * M1 + (9 * M1) / 2;
    float* st1 = sm;
    float* st2 = sm + 1024;
    float* st3 = sm + 2048;
    float* st4 = sm + 3072;
    float* st5 = sm + 4096;
    float* st6 = sm + 5120;

    prep_split_k<<<2688, 256, 0, stream>>>(Wq, Wk, Wv, Wo, fg_w1, cw2, cw3, wt, sm);
    transpose_split_k<<<dim3(NN / 32, CC / 32, BB), dim3(32, 8), 0, stream>>>(hoch, X, Xh, Xl);

    const int Mrows = BB * NN;  // 8192
    for (int l = 0; l < LL; ++l) {
        qkv_h_k<<<dim3(12, Mrows / 128), 256, 0, stream>>>(Xh, Xl, wt, l, Qh, Ql, Kh, Kl, Vh, Vl);
        attn7_k<<<dim3(NN / 64, BB * HH), 256, 0, stream>>>(Qh, Ql, Kh, Kl, Vh, Vl);
        int slot = (l * 4 + 3) * 2;
        gemm_h_k<128><<<dim3(CC / 64, Mrows / 128), 256, 0, stream>>>(
            Qh, Ql, wt + (size_t)slot * WT_SLOT, wt + (size_t)(slot + 1) * WT_SLOT,
            nullptr, bA, CC, CC, nullptr);
        add_ln_k<<<Mrows / 4, 256, 0, stream>>>(X, bA, ln_g + l * CC, ln_b + l * CC, Xh, Xl);
    }

    // fg head: 256 -> 64 -> 32 -> 16; stats fused in epilogues, BN fused forward
    gemm_h_k<64><<<dim3(1, Mrows / 64), 256, 0, stream>>>(Xh, Xl, wt + FG1H_OFF, wt + FG1L_OFF, fg_b1, bA, 64, 256, st1);
    gemm_k<true, true><<<dim3(1, Mrows / 64), 256, 0, stream>>>(bA, fg_w2, fg_b2, bB, Mrows, 32, 64,
                                                                st1, fg_g1, fg_be1, INV_MF, st2);
    gemm_k<true, true><<<dim3(1, Mrows / 64), 256, 0, stream>>>(bB, fg_w3, fg_b3, bC, Mrows, 16, 32,
                                                                st2, fg_g2, fg_be2, INV_MF, st3);

    // selection + grouping + conv1 (3->64) fused
    select_k<<<BB * SS, 64, 0, stream>>>(bC, pts, st3, fg_g3, fg_be3, cw1, bA, st4);

    // conv stack (MFMA, input-BN+LeakyReLU fused in staging): 64 -> 256 -> 512
    const int Mg = BB * SS * KK;  // 2112 = 33*64
    gemm_hbn_k<<<dim3(4, Mg / 64), 256, 0, stream>>>(bA, wt + CW2H_OFF, wt + CW2L_OFF,
                                                     bB, 256, 64, st4, cg1, cb1, st5);
    gemm_hbn_k<<<dim3(8, Mg / 64), 256, 0, stream>>>(bB, wt + CW3H_OFF, wt + CW3L_OFF,
                                                     bC, 512, 256, st5, cg2, cb2, st6);

    // fused BN(C3)+LeakyReLU+maxpool
    maxpool_k<<<(BB * 512 * SS + 255) / 256, 256, 0, stream>>>(bC, st6, cg3, cb3, out);

    (void)in_sizes; (void)n_in; (void)out_size; (void)ws_size;
}